// Round 1
// baseline (1415.624 us; speedup 1.0000x reference)
//
#include <hip/hip_runtime.h>
#include <math.h>

#define NTAB 9801

// ---------------------------------------------------------------------------
// Kernel 1: AGGD gamma lookup tables (matches numpy float64 computation)
// ---------------------------------------------------------------------------
__global__ __launch_bounds__(256) void build_tables_k(float* __restrict__ rgam,
                                                      float* __restrict__ gam) {
    int i = blockIdx.x * 256 + threadIdx.x;
    if (i >= NTAB) return;
    double g = 0.2 + (double)i * 0.001;
    double v = exp(2.0 * lgamma(2.0 / g) - lgamma(1.0 / g) - lgamma(3.0 / g));
    rgam[i] = (float)v;
    gam[i]  = (float)g;
}

// ---------------------------------------------------------------------------
// Kernel 2: 3x3 gaussian blur (sigma=0.5, zero pad) + stride-2 decimation
// src: [32,960,960] -> dst: [32,480,480]
// ---------------------------------------------------------------------------
__global__ __launch_bounds__(256) void down_k(const float* __restrict__ src,
                                              float* __restrict__ dst) {
    __shared__ float w[9];
    if (threadIdx.x == 0) {
        double wt[9]; double s = 0.0;
        for (int a = 0; a < 3; a++)
            for (int c = 0; c < 3; c++) {
                int dy = a - 1, dx = c - 1;
                double v = exp(-(double)(dx * dx + dy * dy) * 2.0); // 2*sigma^2 = 0.5
                wt[a * 3 + c] = v; s += v;
            }
        for (int i = 0; i < 9; i++) w[i] = (float)(wt[i] / s);
    }
    __syncthreads();
    const int total = 32 * 480 * 480;
    for (int idx = blockIdx.x * 256 + threadIdx.x; idx < total; idx += gridDim.x * 256) {
        int b = idx / (480 * 480);
        int r = idx % (480 * 480);
        int y = r / 480, x = r % 480;
        const float* s0 = src + (size_t)b * 960 * 960;
        float acc = 0.f;
        for (int a = 0; a < 3; a++) {
            int gy = 2 * y + a - 1;
            if (gy < 0 || gy >= 960) continue;
            for (int c = 0; c < 3; c++) {
                int gx = 2 * x + c - 1;
                if (gx < 0 || gx >= 960) continue;
                acc += w[a * 3 + c] * s0[gy * 960 + gx];
            }
        }
        dst[idx] = acc;
    }
}

// ---------------------------------------------------------------------------
// Kernel 3: fused MSCN + AGGD features for one 96x96 (or 48x48) block.
// One workgroup (256 thr) per (batch, block). Writes 18 features at foff.
// ---------------------------------------------------------------------------
template <int BS>
__global__ __launch_bounds__(256) void feat_k(const float* __restrict__ src, int S,
                                              const float* __restrict__ rgam,
                                              const float* __restrict__ gam,
                                              float* __restrict__ dfeat, int foff) {
    constexpr int TS = BS + 6;
    constexpr int NPIX = (BS * BS) / 256;
    __shared__ float tile[TS * TS];
    __shared__ float xn[BS * BS];
    __shared__ float w7[49];
    __shared__ float red[20];   // 4 waves x 5 partial sums
    __shared__ float tot[5];
    __shared__ float wbd[4];
    __shared__ int   wbi[4];
    __shared__ int   aidx_sh;

    const int tid = threadIdx.x;
    const int b   = blockIdx.x / 100;
    const int blk = blockIdx.x % 100;
    const int by  = (blk / 10) * BS;
    const int bx  = (blk % 10) * BS;

    // 7x7 gaussian window (sigma=7/6), computed in double, normalized, ->f32
    if (tid == 0) {
        double wt[49]; double s = 0.0;
        const double sg = 7.0 / 6.0;
        for (int i = 0; i < 49; i++) {
            int dy = i / 7 - 3, dx = i % 7 - 3;
            double v = exp(-(double)(dx * dx + dy * dy) / (2.0 * sg * sg));
            wt[i] = v; s += v;
        }
        for (int i = 0; i < 49; i++) w7[i] = (float)(wt[i] / s);
    }

    // load tile with replicate (edge) clamping
    const float* img = src + (size_t)b * S * S;
    for (int i = tid; i < TS * TS; i += 256) {
        int ty = i / TS, tx = i % TS;
        int gy = by + ty - 3; gy = gy < 0 ? 0 : (gy >= S ? S - 1 : gy);
        int gx = bx + tx - 3; gx = gx < 0 ? 0 : (gx >= S ? S - 1 : gx);
        tile[i] = img[(size_t)gy * S + gx];
    }
    __syncthreads();

    // MSCN: xn = (v - mu) / (sigma + 1)
    for (int k = 0; k < NPIX; k++) {
        int p = tid + k * 256;
        int y = p / BS, x = p % BS;
        float s1 = 0.f, s2 = 0.f;
#pragma unroll
        for (int dy = 0; dy < 7; dy++)
#pragma unroll
            for (int dx = 0; dx < 7; dx++) {
                float w = w7[dy * 7 + dx];
                float v = tile[(y + dy) * TS + (x + dx)];
                s1 += w * v;
                s2 += w * v * v;
            }
        float v0  = tile[(y + 3) * TS + (x + 3)];
        float sig = sqrtf(fabsf(s2 - s1 * s1));
        xn[p] = (v0 - s1) / (sig + 1.0f);
    }
    __syncthreads();

    const int SY[5] = {0, 0, 1, 1, 1};
    const int SX[5] = {0, 1, 0, 1, -1};
    const int wid = tid >> 6, lane = tid & 63;

    for (int v = 0; v < 5; v++) {
        float cntl = 0.f, cntr = 0.f, sql = 0.f, sqr = 0.f, sabs = 0.f;
        const int sy = SY[v], sx = SX[v];
        for (int k = 0; k < NPIX; k++) {
            int p = tid + k * 256;
            int y = p / BS, x = p % BS;
            float val = xn[p];
            if (v > 0) {
                int ys = y - sy; if (ys < 0) ys += BS;
                int xs = x - sx; if (xs < 0) xs += BS; if (xs >= BS) xs -= BS;
                val *= xn[ys * BS + xs];
            }
            if (val < 0.f)      { cntl += 1.f; sql += val * val; }
            else if (val > 0.f) { cntr += 1.f; sqr += val * val; }
            sabs += fabsf(val);
        }
        // wave reduce (64 lanes)
        for (int off = 32; off >= 1; off >>= 1) {
            cntl += __shfl_down(cntl, off);
            cntr += __shfl_down(cntr, off);
            sql  += __shfl_down(sql,  off);
            sqr  += __shfl_down(sqr,  off);
            sabs += __shfl_down(sabs, off);
        }
        if (lane == 0) {
            red[wid * 5 + 0] = cntl; red[wid * 5 + 1] = cntr;
            red[wid * 5 + 2] = sql;  red[wid * 5 + 3] = sqr;
            red[wid * 5 + 4] = sabs;
        }
        __syncthreads();
        if (tid == 0)
            for (int j = 0; j < 5; j++)
                tot[j] = red[j] + red[5 + j] + red[10 + j] + red[15 + j];
        __syncthreads();

        float tcl = tot[0], tcr = tot[1], tsql = tot[2], tsqr = tot[3], tsabs = tot[4];
        float cl = fmaxf(tcl, 1.f), cr = fmaxf(tcr, 1.f);
        float lstd = sqrtf(tsql / cl), rstd = sqrtf(tsqr / cr);
        float gh = lstd / fmaxf(rstd, 1e-12f);
        const float N = (float)(BS * BS);
        float mabs = tsabs / N, msq = (tsql + tsqr) / N;
        float rhat = (mabs * mabs) / fmaxf(msq, 1e-12f);
        float gh2 = gh * gh;
        float rhn = rhat * (gh * gh2 + 1.f) * (gh + 1.f) / ((gh2 + 1.f) * (gh2 + 1.f));

        // parallel argmin over table, first-index tie-break (jnp.argmin semantics)
        float best = 3.4e38f; int bidx = NTAB - 1;
        for (int i = tid; i < NTAB; i += 256) {
            float d = fabsf(rgam[i] - rhn);
            if (d < best) { best = d; bidx = i; }
        }
        for (int off = 32; off >= 1; off >>= 1) {
            float d2 = __shfl_down(best, off);
            int   i2 = __shfl_down(bidx, off);
            if (d2 < best || (d2 == best && i2 < bidx)) { best = d2; bidx = i2; }
        }
        if (lane == 0) { wbd[wid] = best; wbi[wid] = bidx; }
        __syncthreads();
        if (tid == 0) {
            float bd = wbd[0]; int bi = wbi[0];
            for (int wv = 1; wv < 4; wv++) {
                if (wbd[wv] < bd || (wbd[wv] == bd && wbi[wv] < bi)) { bd = wbd[wv]; bi = wbi[wv]; }
            }
            aidx_sh = bi;
            float alpha = gam[bi];
            float conv  = expf(0.5f * (lgammaf(1.f / alpha) - lgammaf(3.f / alpha)));
            float bl = lstd * conv, br = rstd * conv;
            float* outp = dfeat + ((size_t)b * 100 + blk) * 36 + foff;
            if (v == 0) {
                outp[0] = alpha;
                outp[1] = 0.5f * (bl + br);
            } else {
                float mean = (br - bl) * expf(lgammaf(2.f / alpha) - lgammaf(1.f / alpha));
                int base = 2 + (v - 1) * 4;
                outp[base + 0] = alpha; outp[base + 1] = mean;
                outp[base + 2] = bl;    outp[base + 3] = br;
            }
        }
        __syncthreads();
    }
    (void)aidx_sh;
}

// ---------------------------------------------------------------------------
// Kernel 4: per-batch stats + SPD solve. q = diff^T M^-1 diff via Cholesky.
// ---------------------------------------------------------------------------
__global__ __launch_bounds__(256) void final_k(const float* __restrict__ dfeat,
                                               const float* __restrict__ mu_pris,
                                               const float* __restrict__ cov_pris,
                                               float* __restrict__ out) {
    __shared__ float  ds[3600];
    __shared__ float  mu[36];
    __shared__ double M[1296];
    const int b = blockIdx.x, tid = threadIdx.x;
    const float* src = dfeat + (size_t)b * 3600;
    for (int i = tid; i < 3600; i += 256) ds[i] = src[i];
    __syncthreads();
    if (tid < 36) {
        float s = 0.f;
        for (int n = 0; n < 100; n++) s += ds[n * 36 + tid];
        mu[tid] = s / 100.f;
    }
    __syncthreads();
    for (int e = tid; e < 1296; e += 256) {
        int f = e / 36, g = e % 36;
        float mf = mu[f], mg = mu[g];
        float s = 0.f;
        for (int n = 0; n < 100; n++) s += (ds[n * 36 + f] - mf) * (ds[n * 36 + g] - mg);
        M[e] = 0.5 * ((double)cov_pris[e] + (double)(s / 99.f));
    }
    __syncthreads();
    if (tid == 0) {
        // in-place Cholesky (lower)
        for (int j = 0; j < 36; j++) {
            double d = M[j * 36 + j];
            for (int k = 0; k < j; k++) d -= M[j * 36 + k] * M[j * 36 + k];
            d = sqrt(d);
            M[j * 36 + j] = d;
            for (int i = j + 1; i < 36; i++) {
                double s = M[i * 36 + j];
                for (int k = 0; k < j; k++) s -= M[i * 36 + k] * M[j * 36 + k];
                M[i * 36 + j] = s / d;
            }
        }
        // q = || L^-1 diff ||^2
        double z[36]; double q = 0.0;
        for (int i = 0; i < 36; i++) {
            double s = (double)mu_pris[i] - (double)mu[i];
            for (int k = 0; k < i; k++) s -= M[i * 36 + k] * z[k];
            z[i] = s / M[i * 36 + i];
            q += z[i] * z[i];
        }
        out[b] = sqrtf((float)(q > 0.0 ? q : 0.0));
    }
}

// ---------------------------------------------------------------------------
extern "C" void kernel_launch(void* const* d_in, const int* in_sizes, int n_in,
                              void* d_out, int out_size, void* d_ws, size_t ws_size,
                              hipStream_t stream) {
    const float* X        = (const float*)d_in[0];  // [32,1,960,960]
    const float* mu_pris  = (const float*)d_in[1];  // [36]
    const float* cov_pris = (const float*)d_in[2];  // [36,36]
    float* out = (float*)d_out;                     // [32]

    char* ws = (char*)d_ws;
    float* rgam  = (float*)(ws);                    // 9801 f
    float* gam   = (float*)(ws + 39424);            // 9801 f
    float* dfeat = (float*)(ws + 78848);            // 32*100*36 f
    float* img2  = (float*)(ws + 539648);           // 32*480*480 f

    build_tables_k<<<(NTAB + 255) / 256, 256, 0, stream>>>(rgam, gam);
    feat_k<96><<<3200, 256, 0, stream>>>(X, 960, rgam, gam, dfeat, 0);
    down_k<<<2048, 256, 0, stream>>>(X, img2);
    feat_k<48><<<3200, 256, 0, stream>>>(img2, 480, rgam, gam, dfeat, 18);
    final_k<<<32, 256, 0, stream>>>(dfeat, mu_pris, cov_pris, out);
}

// Round 2
// 771.298 us; speedup vs baseline: 1.8354x; 1.8354x over previous
//
#include <hip/hip_runtime.h>
#include <hip/hip_fp16.h>
#include <math.h>

#define NTAB 9801

// ---------------------------------------------------------------------------
// Kernel 1: AGGD gamma lookup tables (matches numpy float64 computation)
// ---------------------------------------------------------------------------
__global__ __launch_bounds__(256) void build_tables_k(float* __restrict__ rgam,
                                                      float* __restrict__ gam) {
    int i = blockIdx.x * 256 + threadIdx.x;
    if (i >= NTAB) return;
    double g = 0.2 + (double)i * 0.001;
    double v = exp(2.0 * lgamma(2.0 / g) - lgamma(1.0 / g) - lgamma(3.0 / g));
    rgam[i] = (float)v;
    gam[i]  = (float)g;
}

// ---------------------------------------------------------------------------
// Kernel 2: separable MSCN (7x7 gaussian sigma=7/6, replicate pad) computed as
// horizontal then vertical 1D passes; optional fused 3x3 blur + stride-2
// decimation (zero pad) for the pyramid. 48x48 output tile per workgroup.
// xn written as f16 (tolerance headroom is large).
// ---------------------------------------------------------------------------
template <int S, bool FUSE_DOWN>
__global__ __launch_bounds__(256) void mscn_k(const float* __restrict__ src,
                                              __half* __restrict__ xn_out,
                                              float* __restrict__ down_out) {
    constexpr int T = 48, H = T + 6;     // 48x48 tile, 54x54 with halo
    constexpr int NT = S / T;
    __shared__ float tin[H * H];         // 11.7 KB
    __shared__ float h1s[H * T];         // 10.4 KB  (sum w*v,   horizontal)
    __shared__ float h2s[H * T];         // 10.4 KB  (sum w*v*v, horizontal)

    const int tid = threadIdx.x;
    const int b   = blockIdx.x / (NT * NT);
    const int t   = blockIdx.x % (NT * NT);
    const int ty0 = (t / NT) * T;
    const int tx0 = (t % NT) * T;

    // 1D gaussian (sigma 7/6), per-thread in registers, double->f32
    float w1[7];
    {
        double wt[7], s = 0.0;
        const double sg = 7.0 / 6.0;
        for (int i = 0; i < 7; i++) { double d = i - 3; wt[i] = exp(-d * d / (2.0 * sg * sg)); s += wt[i]; }
        for (int i = 0; i < 7; i++) w1[i] = (float)(wt[i] / s);
    }

    const float* img = src + (size_t)b * S * S;
    for (int i = tid; i < H * H; i += 256) {
        int r = i / H, c = i % H;
        int gy = ty0 + r - 3; gy = gy < 0 ? 0 : (gy >= S ? S - 1 : gy);
        int gx = tx0 + c - 3; gx = gx < 0 ? 0 : (gx >= S ? S - 1 : gx);
        tin[i] = img[(size_t)gy * S + gx];
    }
    __syncthreads();

    // horizontal pass: all 54 rows x 48 center columns
    for (int i = tid; i < H * T; i += 256) {
        int r = i / T, c = i % T;
        const float* row = &tin[r * H + c];
        float s1 = 0.f, s2 = 0.f;
#pragma unroll
        for (int dx = 0; dx < 7; dx++) { float v = row[dx]; s1 += w1[dx] * v; s2 += w1[dx] * v * v; }
        h1s[i] = s1; h2s[i] = s2;
    }
    __syncthreads();

    // vertical pass + MSCN + write
    for (int i = tid; i < T * T; i += 256) {
        int r = i / T, c = i % T;
        float s1 = 0.f, s2 = 0.f;
#pragma unroll
        for (int dy = 0; dy < 7; dy++) {
            s1 += w1[dy] * h1s[(r + dy) * T + c];
            s2 += w1[dy] * h2s[(r + dy) * T + c];
        }
        float v0  = tin[(r + 3) * H + (c + 3)];
        float sig = sqrtf(fabsf(s2 - s1 * s1));
        xn_out[((size_t)b * S + (ty0 + r)) * S + (tx0 + c)] = __float2half((v0 - s1) / (sig + 1.0f));
    }

    if constexpr (FUSE_DOWN) {
        float w3[9];
        {
            double wt[9], s = 0.0;
            for (int a = 0; a < 3; a++)
                for (int c2 = 0; c2 < 3; c2++) { int dy = a - 1, dx = c2 - 1; double v = exp(-2.0 * (dx * dx + dy * dy)); wt[a * 3 + c2] = v; s += v; }
            for (int i = 0; i < 9; i++) w3[i] = (float)(wt[i] / s);
        }
        constexpr int TD = T / 2;  // 24x24 downsampled outputs per tile
        for (int i = tid; i < TD * TD; i += 256) {
            int yy = i / TD, xx = i % TD;
            int Y = ty0 / 2 + yy, X = tx0 / 2 + xx;
            float acc = 0.f;
            for (int a = 0; a < 3; a++) {
                int gy = 2 * Y + a - 1;
                if (gy < 0 || gy >= S) continue;          // zero pad
                int ly = gy - ty0 + 3;
                for (int c2 = 0; c2 < 3; c2++) {
                    int gx = 2 * X + c2 - 1;
                    if (gx < 0 || gx >= S) continue;      // zero pad
                    acc += w3[a * 3 + c2] * tin[ly * H + (gx - tx0 + 3)];
                }
            }
            down_out[((size_t)b * (S / 2) + Y) * (S / 2) + X] = acc;
        }
    }
}

// ---------------------------------------------------------------------------
// Kernel 3: AGGD features for one block. Loads precomputed MSCN block (f16),
// single pass accumulating all 5 variants x 5 sums, fused 5-way table argmin.
// ---------------------------------------------------------------------------
template <int BS>
__global__ __launch_bounds__(256) void feat2_k(const __half* __restrict__ xnimg, int S,
                                               const float* __restrict__ rgam,
                                               const float* __restrict__ gam,
                                               float* __restrict__ dfeat, int foff) {
    constexpr int NPIX = (BS * BS) / 256;
    __shared__ float xs[BS * BS];
    __shared__ float red[4 * 25];     // [wave][variant*5+stat]
    __shared__ float tot[25];
    __shared__ float wbd[4 * 5];
    __shared__ int   wbi[4 * 5];

    const int tid = threadIdx.x;
    const int b   = blockIdx.x / 100;
    const int blk = blockIdx.x % 100;
    const int by  = (blk / 10) * BS;
    const int bx  = (blk % 10) * BS;

    const __half* img = xnimg + ((size_t)b * S + by) * S + bx;
    for (int i = tid; i < BS * BS; i += 256) {
        int y = i / BS, x = i % BS;
        xs[i] = __half2float(img[(size_t)y * S + x]);
    }
    __syncthreads();

    float a_cl[5], a_cr[5], a_sl[5], a_sr[5], a_ab[5];
#pragma unroll
    for (int v = 0; v < 5; v++) { a_cl[v] = a_cr[v] = a_sl[v] = a_sr[v] = a_ab[v] = 0.f; }

    for (int k = 0; k < NPIX; k++) {
        int p = tid + k * 256;
        int y = p / BS, x = p % BS;
        int ym1 = y ? y - 1 : BS - 1;
        int xm1 = x ? x - 1 : BS - 1;
        int xp1 = (x + 1 == BS) ? 0 : x + 1;
        float v0  = xs[p];
        float vals[5];
        vals[0] = v0;
        vals[1] = v0 * xs[y * BS + xm1];      // shift (0,1)
        vals[2] = v0 * xs[ym1 * BS + x];      // shift (1,0)
        vals[3] = v0 * xs[ym1 * BS + xm1];    // shift (1,1)
        vals[4] = v0 * xs[ym1 * BS + xp1];    // shift (1,-1)
#pragma unroll
        for (int v = 0; v < 5; v++) {
            float val = vals[v], v2 = val * val;
            if (val < 0.f)      { a_cl[v] += 1.f; a_sl[v] += v2; }
            else if (val > 0.f) { a_cr[v] += 1.f; a_sr[v] += v2; }
            a_ab[v] += fabsf(val);
        }
    }

    const int wid = tid >> 6, lane = tid & 63;
#pragma unroll
    for (int v = 0; v < 5; v++) {
        float c0 = a_cl[v], c1 = a_cr[v], s0 = a_sl[v], s1 = a_sr[v], s2 = a_ab[v];
        for (int off = 32; off >= 1; off >>= 1) {
            c0 += __shfl_down(c0, off); c1 += __shfl_down(c1, off);
            s0 += __shfl_down(s0, off); s1 += __shfl_down(s1, off);
            s2 += __shfl_down(s2, off);
        }
        if (lane == 0) {
            red[wid * 25 + v * 5 + 0] = c0; red[wid * 25 + v * 5 + 1] = c1;
            red[wid * 25 + v * 5 + 2] = s0; red[wid * 25 + v * 5 + 3] = s1;
            red[wid * 25 + v * 5 + 4] = s2;
        }
    }
    __syncthreads();
    if (tid < 25) tot[tid] = red[tid] + red[25 + tid] + red[50 + tid] + red[75 + tid];
    __syncthreads();

    // all threads compute the 5 thread-uniform rhn targets
    const float N = (float)(BS * BS);
    float rhn[5];
#pragma unroll
    for (int v = 0; v < 5; v++) {
        float tcl = tot[v * 5 + 0], tcr = tot[v * 5 + 1];
        float tsl = tot[v * 5 + 2], tsr = tot[v * 5 + 3], tab = tot[v * 5 + 4];
        float cl = fmaxf(tcl, 1.f), cr = fmaxf(tcr, 1.f);
        float lstd = sqrtf(tsl / cl), rstd = sqrtf(tsr / cr);
        float gh = lstd / fmaxf(rstd, 1e-12f);
        float mabs = tab / N, msq = (tsl + tsr) / N;
        float rhat = (mabs * mabs) / fmaxf(msq, 1e-12f);
        float gh2 = gh * gh;
        rhn[v] = rhat * (gh * gh2 + 1.f) * (gh + 1.f) / ((gh2 + 1.f) * (gh2 + 1.f));
    }

    // fused 5-way argmin over the table (first-index tie-break = jnp.argmin)
    float best[5]; int bidx[5];
#pragma unroll
    for (int v = 0; v < 5; v++) { best[v] = 3.4e38f; bidx[v] = NTAB - 1; }
    for (int i = tid; i < NTAB; i += 256) {
        float tv = rgam[i];
#pragma unroll
        for (int v = 0; v < 5; v++) {
            float d = fabsf(tv - rhn[v]);
            if (d < best[v]) { best[v] = d; bidx[v] = i; }
        }
    }
#pragma unroll
    for (int v = 0; v < 5; v++) {
        float bd = best[v]; int bi = bidx[v];
        for (int off = 32; off >= 1; off >>= 1) {
            float d2 = __shfl_down(bd, off);
            int   i2 = __shfl_down(bi, off);
            if (d2 < bd || (d2 == bd && i2 < bi)) { bd = d2; bi = i2; }
        }
        if (lane == 0) { wbd[wid * 5 + v] = bd; wbi[wid * 5 + v] = bi; }
    }
    __syncthreads();

    // 5 threads finalize (one per variant): lgammaf-heavy tail parallelized
    if (tid < 5) {
        const int v = tid;
        float bd = wbd[v]; int bi = wbi[v];
        for (int w = 1; w < 4; w++) {
            float d = wbd[w * 5 + v]; int i2 = wbi[w * 5 + v];
            if (d < bd || (d == bd && i2 < bi)) { bd = d; bi = i2; }
        }
        float tcl = tot[v * 5 + 0], tcr = tot[v * 5 + 1];
        float tsl = tot[v * 5 + 2], tsr = tot[v * 5 + 3];
        float cl = fmaxf(tcl, 1.f), cr = fmaxf(tcr, 1.f);
        float lstd = sqrtf(tsl / cl), rstd = sqrtf(tsr / cr);
        float alpha = gam[bi];
        float conv  = expf(0.5f * (lgammaf(1.f / alpha) - lgammaf(3.f / alpha)));
        float bl = lstd * conv, br = rstd * conv;
        float* outp = dfeat + ((size_t)b * 100 + blk) * 36 + foff;
        if (v == 0) {
            outp[0] = alpha;
            outp[1] = 0.5f * (bl + br);
        } else {
            float mean = (br - bl) * expf(lgammaf(2.f / alpha) - lgammaf(1.f / alpha));
            int base = 2 + (v - 1) * 4;
            outp[base + 0] = alpha; outp[base + 1] = mean;
            outp[base + 2] = bl;    outp[base + 3] = br;
        }
    }
}

// ---------------------------------------------------------------------------
// Kernel 4: per-batch stats + SPD solve. q = diff^T M^-1 diff via Cholesky.
// ---------------------------------------------------------------------------
__global__ __launch_bounds__(256) void final_k(const float* __restrict__ dfeat,
                                               const float* __restrict__ mu_pris,
                                               const float* __restrict__ cov_pris,
                                               float* __restrict__ out) {
    __shared__ float  ds[3600];
    __shared__ float  mu[36];
    __shared__ double M[1296];
    const int b = blockIdx.x, tid = threadIdx.x;
    const float* src = dfeat + (size_t)b * 3600;
    for (int i = tid; i < 3600; i += 256) ds[i] = src[i];
    __syncthreads();
    if (tid < 36) {
        float s = 0.f;
        for (int n = 0; n < 100; n++) s += ds[n * 36 + tid];
        mu[tid] = s / 100.f;
    }
    __syncthreads();
    for (int e = tid; e < 1296; e += 256) {
        int f = e / 36, g = e % 36;
        float mf = mu[f], mg = mu[g];
        float s = 0.f;
        for (int n = 0; n < 100; n++) s += (ds[n * 36 + f] - mf) * (ds[n * 36 + g] - mg);
        M[e] = 0.5 * ((double)cov_pris[e] + (double)(s / 99.f));
    }
    __syncthreads();
    if (tid == 0) {
        for (int j = 0; j < 36; j++) {
            double d = M[j * 36 + j];
            for (int k = 0; k < j; k++) d -= M[j * 36 + k] * M[j * 36 + k];
            d = sqrt(d);
            M[j * 36 + j] = d;
            for (int i = j + 1; i < 36; i++) {
                double s = M[i * 36 + j];
                for (int k = 0; k < j; k++) s -= M[i * 36 + k] * M[j * 36 + k];
                M[i * 36 + j] = s / d;
            }
        }
        double z[36]; double q = 0.0;
        for (int i = 0; i < 36; i++) {
            double s = (double)mu_pris[i] - (double)mu[i];
            for (int k = 0; k < i; k++) s -= M[i * 36 + k] * z[k];
            z[i] = s / M[i * 36 + i];
            q += z[i] * z[i];
        }
        out[b] = sqrtf((float)(q > 0.0 ? q : 0.0));
    }
}

// ---------------------------------------------------------------------------
extern "C" void kernel_launch(void* const* d_in, const int* in_sizes, int n_in,
                              void* d_out, int out_size, void* d_ws, size_t ws_size,
                              hipStream_t stream) {
    const float* X        = (const float*)d_in[0];  // [32,1,960,960]
    const float* mu_pris  = (const float*)d_in[1];  // [36]
    const float* cov_pris = (const float*)d_in[2];  // [36,36]
    float* out = (float*)d_out;                     // [32]

    char* ws = (char*)d_ws;
    float*  rgam   = (float*)(ws);                      // 9801 f
    float*  gam    = (float*)(ws + 39424);              // 9801 f
    float*  dfeat  = (float*)(ws + 78848);              // 32*100*36 f = 460800 B
    __half* xn960  = (__half*)(ws + 539648);            // 32*960*960 h = 58982400 B
    float*  img480 = (float*)(ws + 59522048);           // 32*480*480 f = 29491200 B
    __half* xn480  = (__half*)(ws + 89013248);          // 32*480*480 h = 14745600 B
    // total ~103.8 MB

    build_tables_k<<<(NTAB + 255) / 256, 256, 0, stream>>>(rgam, gam);
    mscn_k<960, true ><<<32 * 400, 256, 0, stream>>>(X, xn960, img480);
    feat2_k<96><<<3200, 256, 0, stream>>>(xn960, 960, rgam, gam, dfeat, 0);
    mscn_k<480, false><<<32 * 100, 256, 0, stream>>>(img480, xn480, nullptr);
    feat2_k<48><<<3200, 256, 0, stream>>>(xn480, 480, rgam, gam, dfeat, 18);
    final_k<<<32, 256, 0, stream>>>(dfeat, mu_pris, cov_pris, out);
}

// Round 3
// 399.598 us; speedup vs baseline: 3.5426x; 1.9302x over previous
//
#include <hip/hip_runtime.h>
#include <hip/hip_fp16.h>
#include <math.h>

#define NTAB 9801

// ---------------------------------------------------------------------------
// Kernel 1: AGGD gamma lookup tables (matches numpy float64 computation)
// ---------------------------------------------------------------------------
__global__ __launch_bounds__(256) void build_tables_k(float* __restrict__ rgam,
                                                      float* __restrict__ gam) {
    int i = blockIdx.x * 256 + threadIdx.x;
    if (i >= NTAB) return;
    double g = 0.2 + (double)i * 0.001;
    double v = exp(2.0 * lgamma(2.0 / g) - lgamma(1.0 / g) - lgamma(3.0 / g));
    rgam[i] = (float)v;
    gam[i]  = (float)g;
}

// ---------------------------------------------------------------------------
// Kernel 2: separable MSCN (7x7 gaussian sigma=7/6, replicate pad) + optional
// fused 3x3 blur + stride-2 decimation (zero pad). 48x48 tile per workgroup.
// ---------------------------------------------------------------------------
template <int S, bool FUSE_DOWN>
__global__ __launch_bounds__(256) void mscn_k(const float* __restrict__ src,
                                              __half* __restrict__ xn_out,
                                              float* __restrict__ down_out) {
    constexpr int T = 48, H = T + 6;
    constexpr int NT = S / T;
    __shared__ float tin[H * H];
    __shared__ float h1s[H * T];
    __shared__ float h2s[H * T];

    const int tid = threadIdx.x;
    const int b   = blockIdx.x / (NT * NT);
    const int t   = blockIdx.x % (NT * NT);
    const int ty0 = (t / NT) * T;
    const int tx0 = (t % NT) * T;

    float w1[7];
    {
        double wt[7], s = 0.0;
        const double sg = 7.0 / 6.0;
        for (int i = 0; i < 7; i++) { double d = i - 3; wt[i] = exp(-d * d / (2.0 * sg * sg)); s += wt[i]; }
        for (int i = 0; i < 7; i++) w1[i] = (float)(wt[i] / s);
    }

    const float* img = src + (size_t)b * S * S;
    for (int i = tid; i < H * H; i += 256) {
        int r = i / H, c = i % H;
        int gy = ty0 + r - 3; gy = gy < 0 ? 0 : (gy >= S ? S - 1 : gy);
        int gx = tx0 + c - 3; gx = gx < 0 ? 0 : (gx >= S ? S - 1 : gx);
        tin[i] = img[(size_t)gy * S + gx];
    }
    __syncthreads();

    for (int i = tid; i < H * T; i += 256) {
        int r = i / T, c = i % T;
        const float* row = &tin[r * H + c];
        float s1 = 0.f, s2 = 0.f;
#pragma unroll
        for (int dx = 0; dx < 7; dx++) { float v = row[dx]; s1 += w1[dx] * v; s2 += w1[dx] * v * v; }
        h1s[i] = s1; h2s[i] = s2;
    }
    __syncthreads();

    for (int i = tid; i < T * T; i += 256) {
        int r = i / T, c = i % T;
        float s1 = 0.f, s2 = 0.f;
#pragma unroll
        for (int dy = 0; dy < 7; dy++) {
            s1 += w1[dy] * h1s[(r + dy) * T + c];
            s2 += w1[dy] * h2s[(r + dy) * T + c];
        }
        float v0  = tin[(r + 3) * H + (c + 3)];
        float sig = sqrtf(fabsf(s2 - s1 * s1));
        xn_out[((size_t)b * S + (ty0 + r)) * S + (tx0 + c)] = __float2half((v0 - s1) / (sig + 1.0f));
    }

    if constexpr (FUSE_DOWN) {
        float w3[9];
        {
            double wt[9], s = 0.0;
            for (int a = 0; a < 3; a++)
                for (int c2 = 0; c2 < 3; c2++) { int dy = a - 1, dx = c2 - 1; double v = exp(-2.0 * (dx * dx + dy * dy)); wt[a * 3 + c2] = v; s += v; }
            for (int i = 0; i < 9; i++) w3[i] = (float)(wt[i] / s);
        }
        constexpr int TD = T / 2;
        for (int i = tid; i < TD * TD; i += 256) {
            int yy = i / TD, xx = i % TD;
            int Y = ty0 / 2 + yy, X = tx0 / 2 + xx;
            float acc = 0.f;
            for (int a = 0; a < 3; a++) {
                int gy = 2 * Y + a - 1;
                if (gy < 0 || gy >= S) continue;
                int ly = gy - ty0 + 3;
                for (int c2 = 0; c2 < 3; c2++) {
                    int gx = 2 * X + c2 - 1;
                    if (gx < 0 || gx >= S) continue;
                    acc += w3[a * 3 + c2] * tin[ly * H + (gx - tx0 + 3)];
                }
            }
            down_out[((size_t)b * (S / 2) + Y) * (S / 2) + X] = acc;
        }
    }
}

// ---------------------------------------------------------------------------
// Kernel 3: AGGD features per block. f16 LDS tile (identical values to the
// f16 global data -> zero accuracy change, half the LDS, more blocks/CU).
// ---------------------------------------------------------------------------
template <int BS>
__global__ __launch_bounds__(256) void feat2_k(const __half* __restrict__ xnimg, int S,
                                               const float* __restrict__ rgam,
                                               const float* __restrict__ gam,
                                               float* __restrict__ dfeat, int foff) {
    constexpr int NPIX = (BS * BS) / 256;
    __shared__ __half xs[BS * BS];
    __shared__ float red[4 * 25];
    __shared__ float tot[25];
    __shared__ float wbd[4 * 5];
    __shared__ int   wbi[4 * 5];

    const int tid = threadIdx.x;
    const int b   = blockIdx.x / 100;
    const int blk = blockIdx.x % 100;
    const int by  = (blk / 10) * BS;
    const int bx  = (blk % 10) * BS;

    const __half* img = xnimg + ((size_t)b * S + by) * S + bx;
    for (int i = tid; i < BS * BS; i += 256) {
        int y = i / BS, x = i % BS;
        xs[i] = img[(size_t)y * S + x];
    }
    __syncthreads();

    float a_cl[5], a_cr[5], a_sl[5], a_sr[5], a_ab[5];
#pragma unroll
    for (int v = 0; v < 5; v++) { a_cl[v] = a_cr[v] = a_sl[v] = a_sr[v] = a_ab[v] = 0.f; }

    for (int k = 0; k < NPIX; k++) {
        int p = tid + k * 256;
        int y = p / BS, x = p % BS;
        int ym1 = y ? y - 1 : BS - 1;
        int xm1 = x ? x - 1 : BS - 1;
        int xp1 = (x + 1 == BS) ? 0 : x + 1;
        float v0  = __half2float(xs[p]);
        float vals[5];
        vals[0] = v0;
        vals[1] = v0 * __half2float(xs[y * BS + xm1]);
        vals[2] = v0 * __half2float(xs[ym1 * BS + x]);
        vals[3] = v0 * __half2float(xs[ym1 * BS + xm1]);
        vals[4] = v0 * __half2float(xs[ym1 * BS + xp1]);
#pragma unroll
        for (int v = 0; v < 5; v++) {
            float val = vals[v], v2 = val * val;
            if (val < 0.f)      { a_cl[v] += 1.f; a_sl[v] += v2; }
            else if (val > 0.f) { a_cr[v] += 1.f; a_sr[v] += v2; }
            a_ab[v] += fabsf(val);
        }
    }

    const int wid = tid >> 6, lane = tid & 63;
#pragma unroll
    for (int v = 0; v < 5; v++) {
        float c0 = a_cl[v], c1 = a_cr[v], s0 = a_sl[v], s1 = a_sr[v], s2 = a_ab[v];
        for (int off = 32; off >= 1; off >>= 1) {
            c0 += __shfl_down(c0, off); c1 += __shfl_down(c1, off);
            s0 += __shfl_down(s0, off); s1 += __shfl_down(s1, off);
            s2 += __shfl_down(s2, off);
        }
        if (lane == 0) {
            red[wid * 25 + v * 5 + 0] = c0; red[wid * 25 + v * 5 + 1] = c1;
            red[wid * 25 + v * 5 + 2] = s0; red[wid * 25 + v * 5 + 3] = s1;
            red[wid * 25 + v * 5 + 4] = s2;
        }
    }
    __syncthreads();
    if (tid < 25) tot[tid] = red[tid] + red[25 + tid] + red[50 + tid] + red[75 + tid];
    __syncthreads();

    const float N = (float)(BS * BS);
    float rhn[5];
#pragma unroll
    for (int v = 0; v < 5; v++) {
        float tcl = tot[v * 5 + 0], tcr = tot[v * 5 + 1];
        float tsl = tot[v * 5 + 2], tsr = tot[v * 5 + 3], tab = tot[v * 5 + 4];
        float cl = fmaxf(tcl, 1.f), cr = fmaxf(tcr, 1.f);
        float lstd = sqrtf(tsl / cl), rstd = sqrtf(tsr / cr);
        float gh = lstd / fmaxf(rstd, 1e-12f);
        float mabs = tab / N, msq = (tsl + tsr) / N;
        float rhat = (mabs * mabs) / fmaxf(msq, 1e-12f);
        float gh2 = gh * gh;
        rhn[v] = rhat * (gh * gh2 + 1.f) * (gh + 1.f) / ((gh2 + 1.f) * (gh2 + 1.f));
    }

    float best[5]; int bidx[5];
#pragma unroll
    for (int v = 0; v < 5; v++) { best[v] = 3.4e38f; bidx[v] = NTAB - 1; }
    for (int i = tid; i < NTAB; i += 256) {
        float tv = rgam[i];
#pragma unroll
        for (int v = 0; v < 5; v++) {
            float d = fabsf(tv - rhn[v]);
            if (d < best[v]) { best[v] = d; bidx[v] = i; }
        }
    }
#pragma unroll
    for (int v = 0; v < 5; v++) {
        float bd = best[v]; int bi = bidx[v];
        for (int off = 32; off >= 1; off >>= 1) {
            float d2 = __shfl_down(bd, off);
            int   i2 = __shfl_down(bi, off);
            if (d2 < bd || (d2 == bd && i2 < bi)) { bd = d2; bi = i2; }
        }
        if (lane == 0) { wbd[wid * 5 + v] = bd; wbi[wid * 5 + v] = bi; }
    }
    __syncthreads();

    if (tid < 5) {
        const int v = tid;
        float bd = wbd[v]; int bi = wbi[v];
        for (int w = 1; w < 4; w++) {
            float d = wbd[w * 5 + v]; int i2 = wbi[w * 5 + v];
            if (d < bd || (d == bd && i2 < bi)) { bd = d; bi = i2; }
        }
        float tcl = tot[v * 5 + 0], tcr = tot[v * 5 + 1];
        float tsl = tot[v * 5 + 2], tsr = tot[v * 5 + 3];
        float cl = fmaxf(tcl, 1.f), cr = fmaxf(tcr, 1.f);
        float lstd = sqrtf(tsl / cl), rstd = sqrtf(tsr / cr);
        float alpha = gam[bi];
        float conv  = expf(0.5f * (lgammaf(1.f / alpha) - lgammaf(3.f / alpha)));
        float bl = lstd * conv, br = rstd * conv;
        float* outp = dfeat + ((size_t)b * 100 + blk) * 36 + foff;
        if (v == 0) {
            outp[0] = alpha;
            outp[1] = 0.5f * (bl + br);
        } else {
            float mean = (br - bl) * expf(lgammaf(2.f / alpha) - lgammaf(1.f / alpha));
            int base = 2 + (v - 1) * 4;
            outp[base + 0] = alpha; outp[base + 1] = mean;
            outp[base + 2] = bl;    outp[base + 3] = br;
        }
    }
}

// ---------------------------------------------------------------------------
// Kernel 4: per-batch stats + SPD solve via PARALLEL Gaussian elimination.
// q = diff^T M^-1 diff = sum_j y_j^2 / d_j  (y = L^-1 diff, d_j = pivot) —
// no back-substitution needed. Serial depth: 36 steps.
// ---------------------------------------------------------------------------
__global__ __launch_bounds__(256) void final_k(const float* __restrict__ dfeat,
                                               const float* __restrict__ mu_pris,
                                               const float* __restrict__ cov_pris,
                                               float* __restrict__ out) {
    __shared__ float  ds[3600];
    __shared__ float  mu[36];
    __shared__ double M[36][37];   // +1 pad
    __shared__ double rhs[36];
    __shared__ double qacc;
    const int b = blockIdx.x, tid = threadIdx.x;
    const float* src = dfeat + (size_t)b * 3600;
    for (int i = tid; i < 3600; i += 256) ds[i] = src[i];
    __syncthreads();
    if (tid < 36) {
        float s = 0.f;
        for (int n = 0; n < 100; n++) s += ds[n * 36 + tid];
        mu[tid] = s / 100.f;
    }
    __syncthreads();
    // center in place
    for (int i = tid; i < 3600; i += 256) ds[i] -= mu[i % 36];
    if (tid < 36) rhs[tid] = (double)mu_pris[tid] - (double)mu[tid];
    if (tid == 0) qacc = 0.0;
    __syncthreads();
    for (int e = tid; e < 1296; e += 256) {
        int f = e / 36, g = e % 36;
        float s = 0.f;
        for (int n = 0; n < 100; n++) s += ds[n * 36 + f] * ds[n * 36 + g];
        M[f][g] = 0.5 * ((double)cov_pris[e] + (double)(s / 99.f));
    }
    __syncthreads();
    // forward elimination; accumulate q on thread 0
    for (int j = 0; j < 36; j++) {
        if (tid == 0) qacc += rhs[j] * rhs[j] / M[j][j];
        int i = j + 1 + tid;
        if (i < 36) {
            double L = M[i][j] / M[j][j];
            for (int k = j; k < 36; k++) M[i][k] -= L * M[j][k];
            rhs[i] -= L * rhs[j];
        }
        __syncthreads();
    }
    if (tid == 0) out[b] = sqrtf((float)(qacc > 0.0 ? qacc : 0.0));
}

// ---------------------------------------------------------------------------
extern "C" void kernel_launch(void* const* d_in, const int* in_sizes, int n_in,
                              void* d_out, int out_size, void* d_ws, size_t ws_size,
                              hipStream_t stream) {
    const float* X        = (const float*)d_in[0];  // [32,1,960,960]
    const float* mu_pris  = (const float*)d_in[1];  // [36]
    const float* cov_pris = (const float*)d_in[2];  // [36,36]
    float* out = (float*)d_out;                     // [32]

    char* ws = (char*)d_ws;
    float*  rgam   = (float*)(ws);                      // 9801 f
    float*  gam    = (float*)(ws + 39424);              // 9801 f
    float*  dfeat  = (float*)(ws + 78848);              // 32*100*36 f
    __half* xn960  = (__half*)(ws + 539648);            // 32*960*960 h
    float*  img480 = (float*)(ws + 59522048);           // 32*480*480 f
    __half* xn480  = (__half*)(ws + 89013248);          // 32*480*480 h

    build_tables_k<<<(NTAB + 255) / 256, 256, 0, stream>>>(rgam, gam);
    mscn_k<960, true ><<<32 * 400, 256, 0, stream>>>(X, xn960, img480);
    feat2_k<96><<<3200, 256, 0, stream>>>(xn960, 960, rgam, gam, dfeat, 0);
    mscn_k<480, false><<<32 * 100, 256, 0, stream>>>(img480, xn480, nullptr);
    feat2_k<48><<<3200, 256, 0, stream>>>(xn480, 480, rgam, gam, dfeat, 18);
    final_k<<<32, 256, 0, stream>>>(dfeat, mu_pris, cov_pris, out);
}

// Round 4
// 385.089 us; speedup vs baseline: 3.6761x; 1.0377x over previous
//
#include <hip/hip_runtime.h>
#include <hip/hip_fp16.h>
#include <math.h>

#define NTAB 9801

// ---------------------------------------------------------------------------
// Kernel 1: AGGD gamma lookup tables (matches numpy float64 computation)
// ---------------------------------------------------------------------------
__global__ __launch_bounds__(256) void build_tables_k(float* __restrict__ rgam,
                                                      float* __restrict__ gam) {
    int i = blockIdx.x * 256 + threadIdx.x;
    if (i >= NTAB) return;
    double g = 0.2 + (double)i * 0.001;
    double v = exp(2.0 * lgamma(2.0 / g) - lgamma(1.0 / g) - lgamma(3.0 / g));
    rgam[i] = (float)v;
    gam[i]  = (float)g;
}

// ---------------------------------------------------------------------------
// Kernel 2: column-sliding MSCN. Thread = one output column; horizontal 7-tap
// (h1,h2) kept in a 7-deep register ring; vertical pass is register-only.
// LDS holds only the input tile. Optional fused 3x3/stride-2 downsample.
// Tile: 256 cols x 28 rows output, input 262x34 (stride 264).
// ---------------------------------------------------------------------------
template <int S, bool FUSE_DOWN>
__global__ __launch_bounds__(256) void mscn_col_k(const float* __restrict__ src,
                                                  __half* __restrict__ xn_out,
                                                  float* __restrict__ down_out) {
    constexpr int W_OUT = 256, H_OUT = 28;
    constexpr int H_IN = H_OUT + 6;          // 34
    constexpr int STRIDE = 264;              // 262 used, padded for alignment
    constexpr int NTX = (S + W_OUT - 1) / W_OUT;
    constexpr int NTY = (S + H_OUT - 1) / H_OUT;
    __shared__ float tin[STRIDE * H_IN];     // 35.9 KB

    const int tid = threadIdx.x;
    int bid = blockIdx.x;
    const int b  = bid / (NTX * NTY);
    int t2 = bid % (NTX * NTY);
    const int tx = t2 / NTY, ty = t2 % NTY;
    const int x0 = min(tx * W_OUT, S - W_OUT);   // ragged tiles overlap (recompute)
    const int y0 = min(ty * H_OUT, S - H_OUT);

    // 1D gaussian sigma=7/6 (double -> f32, normalized)
    float w1[7];
    {
        double wt[7], s = 0.0;
        const double sg = 7.0 / 6.0;
        for (int i = 0; i < 7; i++) { double d = i - 3; wt[i] = exp(-d * d / (2.0 * sg * sg)); s += wt[i]; }
        for (int i = 0; i < 7; i++) w1[i] = (float)(wt[i] / s);
    }

    // load input tile, replicate-clamped
    const float* img = src + (size_t)b * S * S;
    for (int base = 0; base < STRIDE * H_IN; base += 256) {
        int idx = base + tid;
        if (idx < STRIDE * H_IN) {
            int r = idx / STRIDE, c = idx - r * STRIDE;
            int gy = y0 + r - 3; gy = gy < 0 ? 0 : (gy >= S ? S - 1 : gy);
            int gx = x0 + c - 3; gx = gx < 0 ? 0 : (gx >= S ? S - 1 : gx);
            tin[idx] = img[(size_t)gy * S + gx];
        }
    }
    __syncthreads();

    // register ring of horizontal results for this thread's column
    float r1[7], r2[7];
#pragma unroll
    for (int ir = 0; ir < 6; ir++) {
        const float* p = &tin[ir * STRIDE + tid];
        float s1 = 0.f, s2 = 0.f;
#pragma unroll
        for (int dx = 0; dx < 7; dx++) { float v = p[dx]; s1 += w1[dx] * v; s2 += w1[dx] * v * v; }
        r1[ir] = s1; r2[ir] = s2;
    }

    __half* xnp = xn_out + ((size_t)b * S + y0) * S + x0 + tid;
#pragma unroll
    for (int g = 0; g < H_OUT / 7; g++) {
#pragma unroll
        for (int u = 0; u < 7; u++) {
            const int orow = g * 7 + u;
            {   // new horizontal row into static ring slot (u+6)%7
                const float* p = &tin[(orow + 6) * STRIDE + tid];
                float s1 = 0.f, s2 = 0.f;
#pragma unroll
                for (int dx = 0; dx < 7; dx++) { float v = p[dx]; s1 += w1[dx] * v; s2 += w1[dx] * v * v; }
                r1[(u + 6) % 7] = s1; r2[(u + 6) % 7] = s2;
            }
            float s1 = 0.f, s2 = 0.f;
#pragma unroll
            for (int dy = 0; dy < 7; dy++) {
                s1 += w1[dy] * r1[(u + dy) % 7];
                s2 += w1[dy] * r2[(u + dy) % 7];
            }
            float v0  = tin[(orow + 3) * STRIDE + tid + 3];
            float sig = sqrtf(fabsf(s2 - s1 * s1));
            xnp[(size_t)orow * S] = __float2half((v0 - s1) / (sig + 1.0f));
        }
    }

    if constexpr (FUSE_DOWN) {
        float w3[9];
        {
            double wt[9], s = 0.0;
            for (int a = 0; a < 3; a++)
                for (int c2 = 0; c2 < 3; c2++) { int dy = a - 1, dx = c2 - 1; double v = exp(-2.0 * (dx * dx + dy * dy)); wt[a * 3 + c2] = v; s += v; }
            for (int i = 0; i < 9; i++) w3[i] = (float)(wt[i] / s);
        }
        // 128 down cols x 14 down rows per tile; 2 thread-halves split the rows
        const int d = tid & 127, half = tid >> 7;
        const int Xd = x0 / 2 + d;
        for (int j = half * 7; j < half * 7 + 7; j++) {
            const int Yd = y0 / 2 + j;
            float acc = 0.f;
#pragma unroll
            for (int a = 0; a < 3; a++) {
                int gy = 2 * Yd + a - 1;
                if (gy < 0 || gy >= S) continue;          // zero pad
                int lr = gy - y0 + 3;
#pragma unroll
                for (int c2 = 0; c2 < 3; c2++) {
                    int gx = 2 * Xd + c2 - 1;
                    if (gx < 0 || gx >= S) continue;      // zero pad
                    acc += w3[a * 3 + c2] * tin[lr * STRIDE + (gx - x0 + 3)];
                }
            }
            down_out[((size_t)b * (S / 2) + Yd) * (S / 2) + Xd] = acc;
        }
    }
}

// ---------------------------------------------------------------------------
// Kernel 3: AGGD features per block (f16 LDS tile).
// ---------------------------------------------------------------------------
template <int BS>
__global__ __launch_bounds__(256) void feat2_k(const __half* __restrict__ xnimg, int S,
                                               const float* __restrict__ rgam,
                                               const float* __restrict__ gam,
                                               float* __restrict__ dfeat, int foff) {
    constexpr int NPIX = (BS * BS) / 256;
    __shared__ __half xs[BS * BS];
    __shared__ float red[4 * 25];
    __shared__ float tot[25];
    __shared__ float wbd[4 * 5];
    __shared__ int   wbi[4 * 5];

    const int tid = threadIdx.x;
    const int b   = blockIdx.x / 100;
    const int blk = blockIdx.x % 100;
    const int by  = (blk / 10) * BS;
    const int bx  = (blk % 10) * BS;

    const __half* img = xnimg + ((size_t)b * S + by) * S + bx;
    for (int i = tid; i < BS * BS; i += 256) {
        int y = i / BS, x = i % BS;
        xs[i] = img[(size_t)y * S + x];
    }
    __syncthreads();

    float a_cl[5], a_cr[5], a_sl[5], a_sr[5], a_ab[5];
#pragma unroll
    for (int v = 0; v < 5; v++) { a_cl[v] = a_cr[v] = a_sl[v] = a_sr[v] = a_ab[v] = 0.f; }

    for (int k = 0; k < NPIX; k++) {
        int p = tid + k * 256;
        int y = p / BS, x = p % BS;
        int ym1 = y ? y - 1 : BS - 1;
        int xm1 = x ? x - 1 : BS - 1;
        int xp1 = (x + 1 == BS) ? 0 : x + 1;
        float v0  = __half2float(xs[p]);
        float vals[5];
        vals[0] = v0;
        vals[1] = v0 * __half2float(xs[y * BS + xm1]);
        vals[2] = v0 * __half2float(xs[ym1 * BS + x]);
        vals[3] = v0 * __half2float(xs[ym1 * BS + xm1]);
        vals[4] = v0 * __half2float(xs[ym1 * BS + xp1]);
#pragma unroll
        for (int v = 0; v < 5; v++) {
            float val = vals[v], v2 = val * val;
            if (val < 0.f)      { a_cl[v] += 1.f; a_sl[v] += v2; }
            else if (val > 0.f) { a_cr[v] += 1.f; a_sr[v] += v2; }
            a_ab[v] += fabsf(val);
        }
    }

    const int wid = tid >> 6, lane = tid & 63;
#pragma unroll
    for (int v = 0; v < 5; v++) {
        float c0 = a_cl[v], c1 = a_cr[v], s0 = a_sl[v], s1 = a_sr[v], s2 = a_ab[v];
        for (int off = 32; off >= 1; off >>= 1) {
            c0 += __shfl_down(c0, off); c1 += __shfl_down(c1, off);
            s0 += __shfl_down(s0, off); s1 += __shfl_down(s1, off);
            s2 += __shfl_down(s2, off);
        }
        if (lane == 0) {
            red[wid * 25 + v * 5 + 0] = c0; red[wid * 25 + v * 5 + 1] = c1;
            red[wid * 25 + v * 5 + 2] = s0; red[wid * 25 + v * 5 + 3] = s1;
            red[wid * 25 + v * 5 + 4] = s2;
        }
    }
    __syncthreads();
    if (tid < 25) tot[tid] = red[tid] + red[25 + tid] + red[50 + tid] + red[75 + tid];
    __syncthreads();

    const float N = (float)(BS * BS);
    float rhn[5];
#pragma unroll
    for (int v = 0; v < 5; v++) {
        float tcl = tot[v * 5 + 0], tcr = tot[v * 5 + 1];
        float tsl = tot[v * 5 + 2], tsr = tot[v * 5 + 3], tab = tot[v * 5 + 4];
        float cl = fmaxf(tcl, 1.f), cr = fmaxf(tcr, 1.f);
        float lstd = sqrtf(tsl / cl), rstd = sqrtf(tsr / cr);
        float gh = lstd / fmaxf(rstd, 1e-12f);
        float mabs = tab / N, msq = (tsl + tsr) / N;
        float rhat = (mabs * mabs) / fmaxf(msq, 1e-12f);
        float gh2 = gh * gh;
        rhn[v] = rhat * (gh * gh2 + 1.f) * (gh + 1.f) / ((gh2 + 1.f) * (gh2 + 1.f));
    }

    float best[5]; int bidx[5];
#pragma unroll
    for (int v = 0; v < 5; v++) { best[v] = 3.4e38f; bidx[v] = NTAB - 1; }
    for (int i = tid; i < NTAB; i += 256) {
        float tv = rgam[i];
#pragma unroll
        for (int v = 0; v < 5; v++) {
            float d = fabsf(tv - rhn[v]);
            if (d < best[v]) { best[v] = d; bidx[v] = i; }
        }
    }
#pragma unroll
    for (int v = 0; v < 5; v++) {
        float bd = best[v]; int bi = bidx[v];
        for (int off = 32; off >= 1; off >>= 1) {
            float d2 = __shfl_down(bd, off);
            int   i2 = __shfl_down(bi, off);
            if (d2 < bd || (d2 == bd && i2 < bi)) { bd = d2; bi = i2; }
        }
        if (lane == 0) { wbd[wid * 5 + v] = bd; wbi[wid * 5 + v] = bi; }
    }
    __syncthreads();

    if (tid < 5) {
        const int v = tid;
        float bd = wbd[v]; int bi = wbi[v];
        for (int w = 1; w < 4; w++) {
            float d = wbd[w * 5 + v]; int i2 = wbi[w * 5 + v];
            if (d < bd || (d == bd && i2 < bi)) { bd = d; bi = i2; }
        }
        float tcl = tot[v * 5 + 0], tcr = tot[v * 5 + 1];
        float tsl = tot[v * 5 + 2], tsr = tot[v * 5 + 3];
        float cl = fmaxf(tcl, 1.f), cr = fmaxf(tcr, 1.f);
        float lstd = sqrtf(tsl / cl), rstd = sqrtf(tsr / cr);
        float alpha = gam[bi];
        float conv  = expf(0.5f * (lgammaf(1.f / alpha) - lgammaf(3.f / alpha)));
        float bl = lstd * conv, br = rstd * conv;
        float* outp = dfeat + ((size_t)b * 100 + blk) * 36 + foff;
        if (v == 0) {
            outp[0] = alpha;
            outp[1] = 0.5f * (bl + br);
        } else {
            float mean = (br - bl) * expf(lgammaf(2.f / alpha) - lgammaf(1.f / alpha));
            int base = 2 + (v - 1) * 4;
            outp[base + 0] = alpha; outp[base + 1] = mean;
            outp[base + 2] = bl;    outp[base + 3] = br;
        }
    }
}

// ---------------------------------------------------------------------------
// Kernel 4: per-batch stats + parallel SPD elimination.
// q = sum_j y_j^2 / d_j (forward elimination only, SPD -> no pivoting).
// ---------------------------------------------------------------------------
__global__ __launch_bounds__(256) void final_k(const float* __restrict__ dfeat,
                                               const float* __restrict__ mu_pris,
                                               const float* __restrict__ cov_pris,
                                               float* __restrict__ out) {
    __shared__ float  ds[3600];
    __shared__ float  mu[36];
    __shared__ double M[36][37];
    __shared__ double rhs[36];
    __shared__ double qacc;
    const int b = blockIdx.x, tid = threadIdx.x;
    const float* src = dfeat + (size_t)b * 3600;
    for (int i = tid; i < 3600; i += 256) ds[i] = src[i];
    __syncthreads();
    if (tid < 36) {
        float s = 0.f;
        for (int n = 0; n < 100; n++) s += ds[n * 36 + tid];
        mu[tid] = s / 100.f;
    }
    __syncthreads();
    for (int i = tid; i < 3600; i += 256) ds[i] -= mu[i % 36];
    if (tid < 36) rhs[tid] = (double)mu_pris[tid] - (double)mu[tid];
    if (tid == 0) qacc = 0.0;
    __syncthreads();
    for (int e = tid; e < 1296; e += 256) {
        int f = e / 36, g = e % 36;
        float s = 0.f;
        for (int n = 0; n < 100; n++) s += ds[n * 36 + f] * ds[n * 36 + g];
        M[f][g] = 0.5 * ((double)cov_pris[e] + (double)(s / 99.f));
    }
    __syncthreads();
    for (int j = 0; j < 36; j++) {
        if (tid == 0) qacc += rhs[j] * rhs[j] / M[j][j];
        int i = j + 1 + tid;
        if (i < 36) {
            double L = M[i][j] / M[j][j];
            for (int k = j; k < 36; k++) M[i][k] -= L * M[j][k];
            rhs[i] -= L * rhs[j];
        }
        __syncthreads();
    }
    if (tid == 0) out[b] = sqrtf((float)(qacc > 0.0 ? qacc : 0.0));
}

// ---------------------------------------------------------------------------
extern "C" void kernel_launch(void* const* d_in, const int* in_sizes, int n_in,
                              void* d_out, int out_size, void* d_ws, size_t ws_size,
                              hipStream_t stream) {
    const float* X        = (const float*)d_in[0];  // [32,1,960,960]
    const float* mu_pris  = (const float*)d_in[1];  // [36]
    const float* cov_pris = (const float*)d_in[2];  // [36,36]
    float* out = (float*)d_out;                     // [32]

    char* ws = (char*)d_ws;
    float*  rgam   = (float*)(ws);                      // 9801 f
    float*  gam    = (float*)(ws + 39424);              // 9801 f
    float*  dfeat  = (float*)(ws + 78848);              // 32*100*36 f
    __half* xn960  = (__half*)(ws + 539648);            // 32*960*960 h
    float*  img480 = (float*)(ws + 59522048);           // 32*480*480 f
    __half* xn480  = (__half*)(ws + 89013248);          // 32*480*480 h

    build_tables_k<<<(NTAB + 255) / 256, 256, 0, stream>>>(rgam, gam);
    // 960: NTX=4, NTY=35 -> 140 tiles/batch
    mscn_col_k<960, true ><<<32 * 140, 256, 0, stream>>>(X, xn960, img480);
    // 480: NTX=2, NTY=18 -> 36 tiles/batch
    mscn_col_k<480, false><<<32 * 36, 256, 0, stream>>>(img480, xn480, nullptr);
    feat2_k<96><<<3200, 256, 0, stream>>>(xn960, 960, rgam, gam, dfeat, 0);
    feat2_k<48><<<3200, 256, 0, stream>>>(xn480, 480, rgam, gam, dfeat, 18);
    final_k<<<32, 256, 0, stream>>>(dfeat, mu_pris, cov_pris, out);
}

// Round 5
// 314.378 us; speedup vs baseline: 4.5029x; 1.2249x over previous
//
#include <hip/hip_runtime.h>
#include <hip/hip_fp16.h>
#include <math.h>

#define NTAB 9801
typedef unsigned int uint;

// ---------- packed-half helpers ----------
__device__ inline __half2 u2h2(uint u) { return __builtin_bit_cast(__half2, u); }
__device__ inline uint h22u(__half2 h) { return __builtin_bit_cast(uint, h); }
__device__ inline float flo(uint u) { return __low2float(u2h2(u)); }
__device__ inline float fhi(uint u) { return __high2float(u2h2(u)); }
__device__ inline uint pkmul(uint a, uint b) { return h22u(__hmul2(u2h2(a), u2h2(b))); }
__device__ inline uint pack2(float a, float b) {
    return h22u(__halves2half2(__float2half(a), __float2half(b)));
}
__device__ inline uint algn16(uint hi, uint lo) {   // (hi:lo)>>16  -> v_alignbit
    return (uint)((((unsigned long long)hi << 32) | lo) >> 16);
}
typedef _Float16 h2v __attribute__((ext_vector_type(2)));
__device__ inline float fdot2f(uint a, uint b, float c) {
#if defined(__has_builtin) && __has_builtin(__builtin_amdgcn_fdot2)
    return __builtin_amdgcn_fdot2(__builtin_bit_cast(h2v, a), __builtin_bit_cast(h2v, b), c, false);
#else
    return c + flo(a) * flo(b) + fhi(a) * fhi(b);
#endif
}

// ---------------------------------------------------------------------------
// Kernel 1: AGGD gamma lookup tables
// ---------------------------------------------------------------------------
__global__ __launch_bounds__(256) void build_tables_k(float* __restrict__ rgam,
                                                      float* __restrict__ gam) {
    int i = blockIdx.x * 256 + threadIdx.x;
    if (i >= NTAB) return;
    double g = 0.2 + (double)i * 0.001;
    double v = exp(2.0 * lgamma(2.0 / g) - lgamma(1.0 / g) - lgamma(3.0 / g));
    rgam[i] = (float)v;
    gam[i]  = (float)g;
}

// ---------------------------------------------------------------------------
// Kernel 2: MSCN, f16-packed LDS tile, 2 columns/thread, dot2 horizontal conv,
// register-ring vertical conv. Optional fused 3x3/stride-2 downsample (f16 out).
// Tile: 256 output cols x 28 output rows; threads = 128 col-pairs x 2 row-groups.
// ---------------------------------------------------------------------------
template <int S, bool FUSE_DOWN, typename TIN>
__global__ __launch_bounds__(256) void mscn_col_k(const TIN* __restrict__ src,
                                                  uint* __restrict__ xn_out,      // half2 words
                                                  __half* __restrict__ down_out) {
    constexpr int ROW_W = 132, H_IN = 34, H_OUT = 28;
    constexpr int NTX = (S + 255) / 256, NTY = (S + H_OUT - 1) / H_OUT;
    __shared__ uint tin[ROW_W * H_IN];   // 17.9 KB

    const int tid = threadIdx.x;
    const int bid = blockIdx.x;
    const int b  = bid / (NTX * NTY);
    const int t2 = bid % (NTX * NTY);
    const int x0 = min((t2 / NTY) * 256, S - 256);
    const int y0 = min((t2 % NTY) * H_OUT, S - H_OUT);

    float w1[7];
    {
        double wt[7], s = 0.0; const double sg = 7.0 / 6.0;
        for (int i = 0; i < 7; i++) { double d = i - 3; wt[i] = exp(-d * d / (2.0 * sg * sg)); s += wt[i]; }
        for (int i = 0; i < 7; i++) w1[i] = (float)(wt[i] / s);
    }
    uint wA[4], wB[4];
    wA[0] = pack2(w1[0], w1[1]); wA[1] = pack2(w1[2], w1[3]);
    wA[2] = pack2(w1[4], w1[5]); wA[3] = pack2(w1[6], 0.f);
    wB[0] = pack2(0.f, w1[0]);   wB[1] = pack2(w1[1], w1[2]);
    wB[2] = pack2(w1[3], w1[4]); wB[3] = pack2(w1[5], w1[6]);

    // load tile: word w holds gcols (x0+2w-3, x0+2w-2), replicate-clamped
    const TIN* img = src + (size_t)b * S * S;
    for (int i = tid; i < ROW_W * H_IN; i += 256) {
        int r = i / ROW_W, w = i - r * ROW_W;
        int gy = y0 + r - 3; gy = gy < 0 ? 0 : (gy >= S ? S - 1 : gy);
        int c0 = x0 + 2 * w - 3; c0 = c0 < 0 ? 0 : (c0 >= S ? S - 1 : c0);
        int c1 = c0 + 1;        c1 = (x0 + 2 * w - 2) < 0 ? 0 : ((x0 + 2 * w - 2) >= S ? S - 1 : x0 + 2 * w - 2);
        const TIN* rp = img + (size_t)gy * S;
        tin[i] = pack2((float)rp[c0], (float)rp[c1]);
    }
    __syncthreads();

    const int g = tid >> 7, c = tid & 127;
    const int R0 = g * 14;

    // horizontal 7-tap for output col pair (2c, 2c+1): halves [2c..2c+7] = words c..c+3
    auto horiz = [&](int row, float& s1A, float& s2A, float& s1B, float& s2B) {
        const uint* pw = &tin[row * ROW_W + c];
        uint q0 = pw[0], q1 = pw[1], q2 = pw[2], q3 = pw[3];
        uint p0 = pkmul(q0, q0), p1 = pkmul(q1, q1), p2 = pkmul(q2, q2), p3 = pkmul(q3, q3);
        s1A = fdot2f(q3, wA[3], fdot2f(q2, wA[2], fdot2f(q1, wA[1], fdot2f(q0, wA[0], 0.f))));
        s2A = fdot2f(p3, wA[3], fdot2f(p2, wA[2], fdot2f(p1, wA[1], fdot2f(p0, wA[0], 0.f))));
        s1B = fdot2f(q3, wB[3], fdot2f(q2, wB[2], fdot2f(q1, wB[1], fdot2f(q0, wB[0], 0.f))));
        s2B = fdot2f(p3, wB[3], fdot2f(p2, wB[2], fdot2f(p1, wB[1], fdot2f(p0, wB[0], 0.f))));
    };

    float r1A[7], r2A[7], r1B[7], r2B[7];
#pragma unroll
    for (int ir = 0; ir < 6; ir++) horiz(R0 + ir, r1A[ir], r2A[ir], r1B[ir], r2B[ir]);

    uint* xnp = xn_out + ((((size_t)b * S + y0 + R0) * S + x0) >> 1) + c;
#pragma unroll
    for (int u = 0; u < 14; u++) {
        horiz(R0 + u + 6, r1A[(u + 6) % 7], r2A[(u + 6) % 7], r1B[(u + 6) % 7], r2B[(u + 6) % 7]);
        float s1a = 0.f, s2a = 0.f, s1b = 0.f, s2b = 0.f;
#pragma unroll
        for (int dy = 0; dy < 7; dy++) {
            s1a += w1[dy] * r1A[(u + dy) % 7];  s2a += w1[dy] * r2A[(u + dy) % 7];
            s1b += w1[dy] * r1B[(u + dy) % 7];  s2b += w1[dy] * r2B[(u + dy) % 7];
        }
        int row = R0 + u + 3;
        uint cw1 = tin[row * ROW_W + c + 1], cw2 = tin[row * ROW_W + c + 2];
        float v0a = fhi(cw1), v0b = flo(cw2);   // halves 2c+3, 2c+4 = center cols
        float xa = (v0a - s1a) / (sqrtf(fabsf(s2a - s1a * s1a)) + 1.f);
        float xb = (v0b - s1b) / (sqrtf(fabsf(s2b - s1b * s1b)) + 1.f);
        xnp[(size_t)u * (S / 2)] = pack2(xa, xb);
    }

    if constexpr (FUSE_DOWN) {
        // separable 3x3 sigma=0.5, ZERO pad: mask replicated halo at top/left
        float wd[3];
        { double e1 = exp(-2.0), s = 1.0 + 2.0 * e1;
          wd[0] = wd[2] = (float)(e1 / s); wd[1] = (float)(1.0 / s); }
        const int d = tid & 127, hf = tid >> 7;
        const int Xd = x0 / 2 + d;
        const float mL = (x0 + 2 * d - 1 >= 0) ? 1.f : 0.f;
#pragma unroll
        for (int jj = 0; jj < 7; jj++) {
            int j = hf * 7 + jj;
            int Yd = y0 / 2 + j;
            float acc = 0.f;
#pragma unroll
            for (int a = 0; a < 3; a++) {
                int gy = 2 * Yd - 1 + a;
                if (gy < 0) continue;                  // zero pad (uniform branch)
                int tr = gy - y0 + 3;
                uint u1 = tin[tr * ROW_W + d + 1];     // halves 2d+2, 2d+3
                uint u2 = tin[tr * ROW_W + d + 2];     // half  2d+4
                float rs = wd[0] * flo(u1) * mL + wd[1] * fhi(u1) + wd[2] * flo(u2);
                acc += wd[a] * rs;
            }
            down_out[((size_t)b * (S / 2) + Yd) * (S / 2) + Xd] = __float2half(acc);
        }
    }
}

// ---------------------------------------------------------------------------
// Kernel 3: AGGD features, pixel-pair packed processing.
// sums: ssq=Σv², sab=Σ|v|, ssg=Σv|v| (=sqr-sql); counts: negatives via ballot;
// cr = N - cl (zero-products negligible).
// ---------------------------------------------------------------------------
template <int BS>
__global__ __launch_bounds__(256) void feat2_k(const __half* __restrict__ xnimg, int S,
                                               const float* __restrict__ rgam,
                                               const float* __restrict__ gam,
                                               float* __restrict__ dfeat, int foff) {
    constexpr int WROW = BS / 2;
    constexpr int NWORD = BS * BS / 2;
    constexpr int NITER = (NWORD + 255) / 256;
    __shared__ uint xs[NWORD];
    __shared__ float red[4 * 20];
    __shared__ float tot[20];
    __shared__ float wbd[4 * 5];
    __shared__ int   wbi[4 * 5];

    const int tid = threadIdx.x;
    const int b   = blockIdx.x / 100;
    const int blk = blockIdx.x % 100;
    const int by  = (blk / 10) * BS;
    const int bx  = (blk % 10) * BS;

    const uint* gw = (const uint*)xnimg;
    for (int i = tid; i < NWORD; i += 256) {
        int y = i / WROW, w = i - y * WROW;
        xs[i] = gw[((((size_t)b * S + by + y) * S + bx) >> 1) + w];
    }
    __syncthreads();

    float ssq[5], sab[5], ssg[5];
    int   cln[5];
#pragma unroll
    for (int v = 0; v < 5; v++) { ssq[v] = sab[v] = ssg[v] = 0.f; cln[v] = 0; }

    const uint ONE2 = 0x3C003C00u;
    const __half hz = __float2half(0.f);

    for (int k = 0; k < NITER; k++) {
        int idx = tid + k * 256;
        if (idx * 2 < BS * BS) {     // wave-uniform (NWORD multiple of 128)
            int p0 = idx * 2;
            int y = p0 / BS;
            int x = p0 - y * BS;     // even
            int w0i = x >> 1;
            int wm = w0i ? w0i - 1 : WROW - 1;
            int wp = (w0i + 1 == WROW) ? 0 : w0i + 1;
            int ym1 = y ? y - 1 : BS - 1;
            int rb = y * WROW, rbm = ym1 * WROW;
            uint V0 = xs[rb + w0i];
            uint WL = xs[rb + wm];
            uint AL = xs[rbm + wm];
            uint AC = xs[rbm + w0i];
            uint AR = xs[rbm + wp];
            uint vv[5];
            vv[0] = V0;
            vv[1] = pkmul(V0, algn16(V0, WL));   // (x-1, x)
            vv[2] = pkmul(V0, AC);               // above (x, x+1)
            vv[3] = pkmul(V0, algn16(AC, AL));   // above (x-1, x)
            vv[4] = pkmul(V0, algn16(AR, AC));   // above (x+1, x+2)
#pragma unroll
            for (int v = 0; v < 5; v++) {
                uint av = vv[v] & 0x7FFF7FFFu;
                ssq[v] = fdot2f(vv[v], vv[v], ssq[v]);
                sab[v] = fdot2f(av, ONE2, sab[v]);
                ssg[v] = fdot2f(vv[v], av, ssg[v]);
                __half2 h = u2h2(vv[v]);
                cln[v] += __popcll(__ballot(__hlt(__low2half(h),  hz)));
                cln[v] += __popcll(__ballot(__hlt(__high2half(h), hz)));
            }
        }
    }

    const int wid = tid >> 6, lane = tid & 63;
#pragma unroll
    for (int v = 0; v < 5; v++) {
        float a = ssq[v], bb = sab[v], cc = ssg[v];
        for (int off = 32; off >= 1; off >>= 1) {
            a += __shfl_down(a, off); bb += __shfl_down(bb, off); cc += __shfl_down(cc, off);
        }
        if (lane == 0) {
            red[wid * 20 + v]      = a;
            red[wid * 20 + 5 + v]  = bb;
            red[wid * 20 + 10 + v] = cc;
            red[wid * 20 + 15 + v] = (float)cln[v];   // wave-uniform
        }
    }
    __syncthreads();
    if (tid < 20) tot[tid] = red[tid] + red[20 + tid] + red[40 + tid] + red[60 + tid];
    __syncthreads();

    const float N = (float)(BS * BS);
    float rhn[5];
#pragma unroll
    for (int v = 0; v < 5; v++) {
        float ssqv = tot[v], sabv = tot[5 + v], ssgv = tot[10 + v], clv = tot[15 + v];
        float sql = fmaxf(0.5f * (ssqv - ssgv), 0.f);
        float sqr = fmaxf(0.5f * (ssqv + ssgv), 0.f);
        float cl = fmaxf(clv, 1.f), cr = fmaxf(N - clv, 1.f);
        float lstd = sqrtf(sql / cl), rstd = sqrtf(sqr / cr);
        float gh = lstd / fmaxf(rstd, 1e-12f);
        float mabs = sabv / N, msq = ssqv / N;
        float rhat = (mabs * mabs) / fmaxf(msq, 1e-12f);
        float gh2 = gh * gh;
        rhn[v] = rhat * (gh * gh2 + 1.f) * (gh + 1.f) / ((gh2 + 1.f) * (gh2 + 1.f));
    }

    float best[5]; int bidx[5];
#pragma unroll
    for (int v = 0; v < 5; v++) { best[v] = 3.4e38f; bidx[v] = NTAB - 1; }
    for (int i = tid; i < NTAB; i += 256) {
        float tv = rgam[i];
#pragma unroll
        for (int v = 0; v < 5; v++) {
            float d = fabsf(tv - rhn[v]);
            if (d < best[v]) { best[v] = d; bidx[v] = i; }
        }
    }
#pragma unroll
    for (int v = 0; v < 5; v++) {
        float bd = best[v]; int bi = bidx[v];
        for (int off = 32; off >= 1; off >>= 1) {
            float d2 = __shfl_down(bd, off);
            int   i2 = __shfl_down(bi, off);
            if (d2 < bd || (d2 == bd && i2 < bi)) { bd = d2; bi = i2; }
        }
        if (lane == 0) { wbd[wid * 5 + v] = bd; wbi[wid * 5 + v] = bi; }
    }
    __syncthreads();

    if (tid < 5) {
        const int v = tid;
        float bd = wbd[v]; int bi = wbi[v];
        for (int w = 1; w < 4; w++) {
            float d = wbd[w * 5 + v]; int i2 = wbi[w * 5 + v];
            if (d < bd || (d == bd && i2 < bi)) { bd = d; bi = i2; }
        }
        float ssqv = tot[v], ssgv = tot[10 + v], clv = tot[15 + v];
        float sql = fmaxf(0.5f * (ssqv - ssgv), 0.f);
        float sqr = fmaxf(0.5f * (ssqv + ssgv), 0.f);
        float cl = fmaxf(clv, 1.f), cr = fmaxf(N - clv, 1.f);
        float lstd = sqrtf(sql / cl), rstd = sqrtf(sqr / cr);
        float alpha = gam[bi];
        float conv  = expf(0.5f * (lgammaf(1.f / alpha) - lgammaf(3.f / alpha)));
        float bl = lstd * conv, br = rstd * conv;
        float* outp = dfeat + ((size_t)b * 100 + blk) * 36 + foff;
        if (v == 0) {
            outp[0] = alpha;
            outp[1] = 0.5f * (bl + br);
        } else {
            float mean = (br - bl) * expf(lgammaf(2.f / alpha) - lgammaf(1.f / alpha));
            int base = 2 + (v - 1) * 4;
            outp[base + 0] = alpha; outp[base + 1] = mean;
            outp[base + 2] = bl;    outp[base + 3] = br;
        }
    }
}

// ---------------------------------------------------------------------------
// Kernel 4: per-batch stats + parallel SPD forward elimination.
// ---------------------------------------------------------------------------
__global__ __launch_bounds__(256) void final_k(const float* __restrict__ dfeat,
                                               const float* __restrict__ mu_pris,
                                               const float* __restrict__ cov_pris,
                                               float* __restrict__ out) {
    __shared__ float  ds[3600];
    __shared__ float  mu[36];
    __shared__ double M[36][37];
    __shared__ double rhs[36];
    __shared__ double qacc;
    const int b = blockIdx.x, tid = threadIdx.x;
    const float* src = dfeat + (size_t)b * 3600;
    for (int i = tid; i < 3600; i += 256) ds[i] = src[i];
    __syncthreads();
    if (tid < 36) {
        float s = 0.f;
        for (int n = 0; n < 100; n++) s += ds[n * 36 + tid];
        mu[tid] = s / 100.f;
    }
    __syncthreads();
    for (int i = tid; i < 3600; i += 256) ds[i] -= mu[i % 36];
    if (tid < 36) rhs[tid] = (double)mu_pris[tid] - (double)mu[tid];
    if (tid == 0) qacc = 0.0;
    __syncthreads();
    for (int e = tid; e < 1296; e += 256) {
        int f = e / 36, g = e % 36;
        float s = 0.f;
        for (int n = 0; n < 100; n++) s += ds[n * 36 + f] * ds[n * 36 + g];
        M[f][g] = 0.5 * ((double)cov_pris[e] + (double)(s / 99.f));
    }
    __syncthreads();
    for (int j = 0; j < 36; j++) {
        if (tid == 0) qacc += rhs[j] * rhs[j] / M[j][j];
        int i = j + 1 + tid;
        if (i < 36) {
            double L = M[i][j] / M[j][j];
            for (int k = j; k < 36; k++) M[i][k] -= L * M[j][k];
            rhs[i] -= L * rhs[j];
        }
        __syncthreads();
    }
    if (tid == 0) out[b] = sqrtf((float)(qacc > 0.0 ? qacc : 0.0));
}

// ---------------------------------------------------------------------------
extern "C" void kernel_launch(void* const* d_in, const int* in_sizes, int n_in,
                              void* d_out, int out_size, void* d_ws, size_t ws_size,
                              hipStream_t stream) {
    const float* X        = (const float*)d_in[0];  // [32,1,960,960]
    const float* mu_pris  = (const float*)d_in[1];  // [36]
    const float* cov_pris = (const float*)d_in[2];  // [36,36]
    float* out = (float*)d_out;                     // [32]

    char* ws = (char*)d_ws;
    float*  rgam   = (float*)(ws);                      // 9801 f
    float*  gam    = (float*)(ws + 39424);
    float*  dfeat  = (float*)(ws + 78848);              // 32*100*36 f
    __half* xn960  = (__half*)(ws + 539648);            // 32*960*960 h = 58,982,400
    __half* img480 = (__half*)(ws + 59522048);          // 32*480*480 h = 14,745,600
    __half* xn480  = (__half*)(ws + 74267648);          // 32*480*480 h
    // end ~89 MB

    build_tables_k<<<(NTAB + 255) / 256, 256, 0, stream>>>(rgam, gam);
    // 960: NTX=4, NTY=35 -> 140 tiles/batch
    mscn_col_k<960, true,  float ><<<32 * 140, 256, 0, stream>>>(X, (uint*)xn960, img480);
    // 480: NTX=2, NTY=18 -> 36 tiles/batch
    mscn_col_k<480, false, __half><<<32 * 36, 256, 0, stream>>>(img480, (uint*)xn480, nullptr);
    feat2_k<96><<<3200, 256, 0, stream>>>(xn960, 960, rgam, gam, dfeat, 0);
    feat2_k<48><<<3200, 256, 0, stream>>>(xn480, 480, rgam, gam, dfeat, 18);
    final_k<<<32, 256, 0, stream>>>(dfeat, mu_pris, cov_pris, out);
}

// Round 6
// 236.721 us; speedup vs baseline: 5.9801x; 1.3281x over previous
//
#include <hip/hip_runtime.h>
#include <hip/hip_fp16.h>
#include <math.h>

#define NTAB 9801
typedef unsigned int uint;

struct WParams { float w1[7]; float wd[3]; };

// ---------- packed-half helpers ----------
__device__ inline __half2 u2h2(uint u) { return __builtin_bit_cast(__half2, u); }
__device__ inline uint h22u(__half2 h) { return __builtin_bit_cast(uint, h); }
__device__ inline float flo(uint u) { return __low2float(u2h2(u)); }
__device__ inline float fhi(uint u) { return __high2float(u2h2(u)); }
__device__ inline uint pkmul(uint a, uint b) { return h22u(__hmul2(u2h2(a), u2h2(b))); }
__device__ inline uint pack2(float a, float b) {
    return h22u(__halves2half2(__float2half(a), __float2half(b)));
}
__device__ inline uint algn16(uint hi, uint lo) {   // (hi:lo)>>16 -> v_alignbit
    return (uint)((((unsigned long long)hi << 32) | lo) >> 16);
}
typedef _Float16 h2v __attribute__((ext_vector_type(2)));
__device__ inline float fdot2f(uint a, uint b, float c) {
#if defined(__has_builtin) && __has_builtin(__builtin_amdgcn_fdot2)
    return __builtin_amdgcn_fdot2(__builtin_bit_cast(h2v, a), __builtin_bit_cast(h2v, b), c, false);
#else
    return c + flo(a) * flo(b) + fhi(a) * fhi(b);
#endif
}

// ---------------------------------------------------------------------------
// Kernel: MSCN (f16-packed LDS tile, 2 cols/thread, dot2 horizontal conv,
// register-ring vertical). Optional fused 3x3/stride-2 downsample (f16 out).
// Optional table-build blocks appended to the grid (TABLES=true).
// Weights are host-computed and passed by value — no per-thread f64.
// ---------------------------------------------------------------------------
template <int S, bool FUSE_DOWN, bool TABLES, typename TIN>
__global__ __launch_bounds__(256) void mscn_col_k(const TIN* __restrict__ src,
                                                  uint* __restrict__ xn_out,
                                                  __half* __restrict__ down_out,
                                                  WParams wp,
                                                  float* __restrict__ rgam,
                                                  float* __restrict__ gam) {
    constexpr int ROW_W = 132, H_IN = 34, H_OUT = 28;
    constexpr int NTX = (S + 255) / 256, NTY = (S + H_OUT - 1) / H_OUT;
    constexpr int NBLK = 32 * NTX * NTY;

    if constexpr (TABLES) {
        if (blockIdx.x >= (unsigned)NBLK) {   // extra blocks build the AGGD tables
            int i = (blockIdx.x - NBLK) * 256 + threadIdx.x;
            if (i < NTAB) {
                double g = 0.2 + (double)i * 0.001;
                double v = exp(2.0 * lgamma(2.0 / g) - lgamma(1.0 / g) - lgamma(3.0 / g));
                rgam[i] = (float)v;
                gam[i]  = (float)g;
            }
            return;
        }
    }

    __shared__ uint tin[ROW_W * H_IN];   // 17.9 KB

    const int tid = threadIdx.x;
    const int bid = blockIdx.x;
    const int b  = bid / (NTX * NTY);
    const int t2 = bid % (NTX * NTY);
    const int x0 = min((t2 / NTY) * 256, S - 256);
    const int y0 = min((t2 % NTY) * H_OUT, S - H_OUT);

    const float* w1 = wp.w1;
    uint wA[4], wB[4];
    wA[0] = pack2(w1[0], w1[1]); wA[1] = pack2(w1[2], w1[3]);
    wA[2] = pack2(w1[4], w1[5]); wA[3] = pack2(w1[6], 0.f);
    wB[0] = pack2(0.f, w1[0]);   wB[1] = pack2(w1[1], w1[2]);
    wB[2] = pack2(w1[3], w1[4]); wB[3] = pack2(w1[5], w1[6]);

    // load tile: word w holds gcols (x0+2w-3, x0+2w-2), replicate-clamped
    const TIN* img = src + (size_t)b * S * S;
    for (int i = tid; i < ROW_W * H_IN; i += 256) {
        int r = i / ROW_W, w = i - r * ROW_W;
        int gy = y0 + r - 3; gy = gy < 0 ? 0 : (gy >= S ? S - 1 : gy);
        int c0 = x0 + 2 * w - 3; c0 = c0 < 0 ? 0 : (c0 >= S ? S - 1 : c0);
        int c1 = (x0 + 2 * w - 2) < 0 ? 0 : ((x0 + 2 * w - 2) >= S ? S - 1 : x0 + 2 * w - 2);
        const TIN* rp = img + (size_t)gy * S;
        tin[i] = pack2((float)rp[c0], (float)rp[c1]);
    }
    __syncthreads();

    const int g = tid >> 7, c = tid & 127;
    const int R0 = g * 14;

    auto horiz = [&](int row, float& s1A, float& s2A, float& s1B, float& s2B) {
        const uint* pw = &tin[row * ROW_W + c];
        uint q0 = pw[0], q1 = pw[1], q2 = pw[2], q3 = pw[3];
        uint p0 = pkmul(q0, q0), p1 = pkmul(q1, q1), p2 = pkmul(q2, q2), p3 = pkmul(q3, q3);
        s1A = fdot2f(q3, wA[3], fdot2f(q2, wA[2], fdot2f(q1, wA[1], fdot2f(q0, wA[0], 0.f))));
        s2A = fdot2f(p3, wA[3], fdot2f(p2, wA[2], fdot2f(p1, wA[1], fdot2f(p0, wA[0], 0.f))));
        s1B = fdot2f(q3, wB[3], fdot2f(q2, wB[2], fdot2f(q1, wB[1], fdot2f(q0, wB[0], 0.f))));
        s2B = fdot2f(p3, wB[3], fdot2f(p2, wB[2], fdot2f(p1, wB[1], fdot2f(p0, wB[0], 0.f))));
    };

    float r1A[7], r2A[7], r1B[7], r2B[7];
#pragma unroll
    for (int ir = 0; ir < 6; ir++) horiz(R0 + ir, r1A[ir], r2A[ir], r1B[ir], r2B[ir]);

    uint* xnp = xn_out + ((((size_t)b * S + y0 + R0) * S + x0) >> 1) + c;
#pragma unroll
    for (int u = 0; u < 14; u++) {
        horiz(R0 + u + 6, r1A[(u + 6) % 7], r2A[(u + 6) % 7], r1B[(u + 6) % 7], r2B[(u + 6) % 7]);
        float s1a = 0.f, s2a = 0.f, s1b = 0.f, s2b = 0.f;
#pragma unroll
        for (int dy = 0; dy < 7; dy++) {
            s1a += w1[dy] * r1A[(u + dy) % 7];  s2a += w1[dy] * r2A[(u + dy) % 7];
            s1b += w1[dy] * r1B[(u + dy) % 7];  s2b += w1[dy] * r2B[(u + dy) % 7];
        }
        int row = R0 + u + 3;
        uint cw1 = tin[row * ROW_W + c + 1], cw2 = tin[row * ROW_W + c + 2];
        float v0a = fhi(cw1), v0b = flo(cw2);   // center cols 2c+3, 2c+4
        float xa = (v0a - s1a) / (sqrtf(fabsf(s2a - s1a * s1a)) + 1.f);
        float xb = (v0b - s1b) / (sqrtf(fabsf(s2b - s1b * s1b)) + 1.f);
        xnp[(size_t)u * (S / 2)] = pack2(xa, xb);
    }

    if constexpr (FUSE_DOWN) {
        const float* wd = wp.wd;
        const int d = tid & 127, hf = tid >> 7;
        const int Xd = x0 / 2 + d;
        const float mL = (x0 + 2 * d - 1 >= 0) ? 1.f : 0.f;
#pragma unroll
        for (int jj = 0; jj < 7; jj++) {
            int j = hf * 7 + jj;
            int Yd = y0 / 2 + j;
            float acc = 0.f;
#pragma unroll
            for (int a = 0; a < 3; a++) {
                int gy = 2 * Yd - 1 + a;
                if (gy < 0) continue;                  // zero pad (uniform branch)
                int tr = gy - y0 + 3;
                uint u1 = tin[tr * ROW_W + d + 1];
                uint u2 = tin[tr * ROW_W + d + 2];
                float rs = wd[0] * flo(u1) * mL + wd[1] * fhi(u1) + wd[2] * flo(u2);
                acc += wd[a] * rs;
            }
            down_out[((size_t)b * (S / 2) + Yd) * (S / 2) + Xd] = __float2half(acc);
        }
    }
}

// ---------------------------------------------------------------------------
// Kernel: AGGD features. Packed pixel-pair sums; negative counts via packed
// sign-bit accumulation; table lookup via binary search (rgam is monotone
// nondecreasing) done by 5 tail threads.
// ---------------------------------------------------------------------------
template <int BS>
__global__ __launch_bounds__(256) void feat2_k(const __half* __restrict__ xnimg, int S,
                                               const float* __restrict__ rgam,
                                               const float* __restrict__ gam,
                                               float* __restrict__ dfeat, int foff) {
    constexpr int WROW = BS / 2;
    constexpr int NWORD = BS * BS / 2;
    constexpr int NITER = (NWORD + 255) / 256;
    __shared__ uint xs[NWORD];
    __shared__ float red[4 * 20];
    __shared__ float tot[20];

    const int tid = threadIdx.x;
    const int b   = blockIdx.x / 100;
    const int blk = blockIdx.x % 100;
    const int by  = (blk / 10) * BS;
    const int bx  = (blk % 10) * BS;

    const uint* gw = (const uint*)xnimg;
    for (int i = tid; i < NWORD; i += 256) {
        int y = i / WROW, w = i - y * WROW;
        xs[i] = gw[((((size_t)b * S + by + y) * S + bx) >> 1) + w];
    }
    __syncthreads();

    float ssq[5], sab[5], ssg[5];
    uint  cnt[5];
#pragma unroll
    for (int v = 0; v < 5; v++) { ssq[v] = sab[v] = ssg[v] = 0.f; cnt[v] = 0u; }

    const uint ONE2 = 0x3C003C00u;

    for (int k = 0; k < NITER; k++) {
        int idx = tid + k * 256;
        if (idx * 2 < BS * BS) {     // wave-uniform (NWORD multiple of 128)
            int p0 = idx * 2;
            int y = p0 / BS;
            int x = p0 - y * BS;     // even
            int w0i = x >> 1;
            int wm = w0i ? w0i - 1 : WROW - 1;
            int wp = (w0i + 1 == WROW) ? 0 : w0i + 1;
            int ym1 = y ? y - 1 : BS - 1;
            int rb = y * WROW, rbm = ym1 * WROW;
            uint V0 = xs[rb + w0i];
            uint WL = xs[rb + wm];
            uint AL = xs[rbm + wm];
            uint AC = xs[rbm + w0i];
            uint AR = xs[rbm + wp];
            uint vv[5];
            vv[0] = V0;
            vv[1] = pkmul(V0, algn16(V0, WL));   // shift (0,1)
            vv[2] = pkmul(V0, AC);               // shift (1,0)
            vv[3] = pkmul(V0, algn16(AC, AL));   // shift (1,1)
            vv[4] = pkmul(V0, algn16(AR, AC));   // shift (1,-1)
#pragma unroll
            for (int v = 0; v < 5; v++) {
                uint av = vv[v] & 0x7FFF7FFFu;
                ssq[v] = fdot2f(vv[v], vv[v], ssq[v]);
                sab[v] = fdot2f(av, ONE2, sab[v]);
                ssg[v] = fdot2f(vv[v], av, ssg[v]);
                cnt[v] += (vv[v] >> 15) & 0x00010001u;   // sign bits, packed
            }
        }
    }

    const int wid = tid >> 6, lane = tid & 63;
#pragma unroll
    for (int v = 0; v < 5; v++) {
        float a = ssq[v], bb = sab[v], cc = ssg[v];
        float dd = (float)((cnt[v] & 0xFFFFu) + (cnt[v] >> 16));
        for (int off = 32; off >= 1; off >>= 1) {
            a += __shfl_down(a, off); bb += __shfl_down(bb, off);
            cc += __shfl_down(cc, off); dd += __shfl_down(dd, off);
        }
        if (lane == 0) {
            red[wid * 20 + v]      = a;
            red[wid * 20 + 5 + v]  = bb;
            red[wid * 20 + 10 + v] = cc;
            red[wid * 20 + 15 + v] = dd;
        }
    }
    __syncthreads();
    if (tid < 20) tot[tid] = red[tid] + red[20 + tid] + red[40 + tid] + red[60 + tid];
    __syncthreads();

    if (tid < 5) {
        const int v = tid;
        const float N = (float)(BS * BS);
        float ssqv = tot[v], sabv = tot[5 + v], ssgv = tot[10 + v], clv = tot[15 + v];
        float sql = fmaxf(0.5f * (ssqv - ssgv), 0.f);
        float sqr = fmaxf(0.5f * (ssqv + ssgv), 0.f);
        float cl = fmaxf(clv, 1.f), cr = fmaxf(N - clv, 1.f);
        float lstd = sqrtf(sql / cl), rstd = sqrtf(sqr / cr);
        float gh = lstd / fmaxf(rstd, 1e-12f);
        float mabs = sabv / N, msq = ssqv / N;
        float rhat = (mabs * mabs) / fmaxf(msq, 1e-12f);
        float gh2 = gh * gh;
        float target = rhat * (gh * gh2 + 1.f) * (gh + 1.f) / ((gh2 + 1.f) * (gh2 + 1.f));

        // binary search: first index with rgam[i] >= target (table monotone)
        int lo = 0, hi = NTAB - 1, j = NTAB;
        while (lo <= hi) {
            int mid = (lo + hi) >> 1;
            if (rgam[mid] >= target) { j = mid; hi = mid - 1; } else lo = mid + 1;
        }
        int i0 = j > 0 ? j - 1 : 0;
        int i1 = j < NTAB ? j : NTAB - 1;
        float d0 = fabsf(rgam[i0] - target);
        float d1 = fabsf(rgam[i1] - target);
        int bi = (d1 < d0) ? i1 : i0;     // tie -> smaller index (argmin-first)

        float alpha = gam[bi];
        float conv  = expf(0.5f * (lgammaf(1.f / alpha) - lgammaf(3.f / alpha)));
        float bl = lstd * conv, br = rstd * conv;
        float* outp = dfeat + ((size_t)b * 100 + blk) * 36 + foff;
        if (v == 0) {
            outp[0] = alpha;
            outp[1] = 0.5f * (bl + br);
        } else {
            float mean = (br - bl) * expf(lgammaf(2.f / alpha) - lgammaf(1.f / alpha));
            int base = 2 + (v - 1) * 4;
            outp[base + 0] = alpha; outp[base + 1] = mean;
            outp[base + 2] = bl;    outp[base + 3] = br;
        }
    }
}

// ---------------------------------------------------------------------------
// Kernel: per-batch stats + parallel SPD forward elimination.
// ---------------------------------------------------------------------------
__global__ __launch_bounds__(256) void final_k(const float* __restrict__ dfeat,
                                               const float* __restrict__ mu_pris,
                                               const float* __restrict__ cov_pris,
                                               float* __restrict__ out) {
    __shared__ float  ds[3600];
    __shared__ float  mu[36];
    __shared__ double M[36][37];
    __shared__ double rhs[36];
    __shared__ double qacc;
    const int b = blockIdx.x, tid = threadIdx.x;
    const float* src = dfeat + (size_t)b * 3600;
    for (int i = tid; i < 3600; i += 256) ds[i] = src[i];
    __syncthreads();
    if (tid < 36) {
        float s = 0.f;
        for (int n = 0; n < 100; n++) s += ds[n * 36 + tid];
        mu[tid] = s / 100.f;
    }
    __syncthreads();
    for (int i = tid; i < 3600; i += 256) ds[i] -= mu[i % 36];
    if (tid < 36) rhs[tid] = (double)mu_pris[tid] - (double)mu[tid];
    if (tid == 0) qacc = 0.0;
    __syncthreads();
    for (int e = tid; e < 1296; e += 256) {
        int f = e / 36, g = e % 36;
        float s = 0.f;
        for (int n = 0; n < 100; n++) s += ds[n * 36 + f] * ds[n * 36 + g];
        M[f][g] = 0.5 * ((double)cov_pris[e] + (double)(s / 99.f));
    }
    __syncthreads();
    for (int j = 0; j < 36; j++) {
        if (tid == 0) qacc += rhs[j] * rhs[j] / M[j][j];
        int i = j + 1 + tid;
        if (i < 36) {
            double L = M[i][j] / M[j][j];
            for (int k = j; k < 36; k++) M[i][k] -= L * M[j][k];
            rhs[i] -= L * rhs[j];
        }
        __syncthreads();
    }
    if (tid == 0) out[b] = sqrtf((float)(qacc > 0.0 ? qacc : 0.0));
}

// ---------------------------------------------------------------------------
static WParams make_weights() {
    WParams p;
    double wt[7], s = 0.0; const double sg = 7.0 / 6.0;
    for (int i = 0; i < 7; i++) { double d = i - 3; wt[i] = exp(-d * d / (2.0 * sg * sg)); s += wt[i]; }
    for (int i = 0; i < 7; i++) p.w1[i] = (float)(wt[i] / s);
    double e1 = exp(-2.0), sd = 1.0 + 2.0 * e1;
    p.wd[0] = p.wd[2] = (float)(e1 / sd);
    p.wd[1] = (float)(1.0 / sd);
    return p;
}

extern "C" void kernel_launch(void* const* d_in, const int* in_sizes, int n_in,
                              void* d_out, int out_size, void* d_ws, size_t ws_size,
                              hipStream_t stream) {
    const float* X        = (const float*)d_in[0];  // [32,1,960,960]
    const float* mu_pris  = (const float*)d_in[1];  // [36]
    const float* cov_pris = (const float*)d_in[2];  // [36,36]
    float* out = (float*)d_out;                     // [32]

    char* ws = (char*)d_ws;
    float*  rgam   = (float*)(ws);                      // 9801 f
    float*  gam    = (float*)(ws + 39424);
    float*  dfeat  = (float*)(ws + 78848);              // 32*100*36 f
    __half* xn960  = (__half*)(ws + 539648);            // 32*960*960 h
    __half* img480 = (__half*)(ws + 59522048);          // 32*480*480 h
    __half* xn480  = (__half*)(ws + 74267648);          // 32*480*480 h

    WParams wp = make_weights();

    constexpr int NB960 = 32 * 4 * 35;                  // 4480 mscn blocks
    constexpr int TBLB  = (NTAB + 255) / 256;           // +39 table blocks
    mscn_col_k<960, true,  true,  float ><<<NB960 + TBLB, 256, 0, stream>>>(
        X, (uint*)xn960, img480, wp, rgam, gam);
    mscn_col_k<480, false, false, __half><<<32 * 36, 256, 0, stream>>>(
        img480, (uint*)xn480, nullptr, wp, rgam, gam);
    feat2_k<96><<<3200, 256, 0, stream>>>(xn960, 960, rgam, gam, dfeat, 0);
    feat2_k<48><<<3200, 256, 0, stream>>>(xn480, 480, rgam, gam, dfeat, 18);
    final_k<<<32, 256, 0, stream>>>(dfeat, mu_pris, cov_pris, out);
}

// Round 7
// 223.236 us; speedup vs baseline: 6.3414x; 1.0604x over previous
//
#include <hip/hip_runtime.h>
#include <hip/hip_fp16.h>
#include <math.h>

#define NTAB 9801
typedef unsigned int uint;
typedef float f2v __attribute__((ext_vector_type(2)));
typedef _Float16 h2v __attribute__((ext_vector_type(2)));

struct WParams { float w1[7]; float wd[3]; };

// ---------- packed-half helpers ----------
__device__ inline __half2 u2h2(uint u) { return __builtin_bit_cast(__half2, u); }
__device__ inline float flo(uint u) { return __low2float(u2h2(u)); }
__device__ inline float fhi(uint u) { return __high2float(u2h2(u)); }
__device__ inline uint pkmul(uint a, uint b) { return __builtin_bit_cast(uint, __hmul2(u2h2(a), u2h2(b))); }
__device__ inline uint pack2(float a, float b) {   // v_cvt_pkrtz_f16_f32: 1 inst
    return __builtin_bit_cast(uint, __builtin_amdgcn_cvt_pkrtz(a, b));
}
__device__ inline uint algn16(uint hi, uint lo) {   // (hi:lo)>>16 -> v_alignbit
    return (uint)((((unsigned long long)hi << 32) | lo) >> 16);
}
__device__ inline float fdot2f(uint a, uint b, float c) {
    return __builtin_amdgcn_fdot2(__builtin_bit_cast(h2v, a), __builtin_bit_cast(h2v, b), c, false);
}
__device__ inline float rcpf(float x) { return __builtin_amdgcn_rcpf(x); }

// ---------------------------------------------------------------------------
// MSCN kernel. f16-packed LDS tile at even-column origin (x0-4) so interior
// tiles stage via aligned float4. 2 output cols/thread; horizontal 7-tap via
// dot2; vertical 7-tap via packed-f32 FMA on a 7-deep register ring.
// Optional fused 3x3/stride-2 downsample (f16, zero-pad). Optional AGGD-table
// builder blocks appended to the grid.
// Word w of a tile row holds image cols (x0-4+2w, x0-3+2w).
// ---------------------------------------------------------------------------
template <int S, bool FUSE_DOWN, bool TABLES, typename TIN>
__global__ __launch_bounds__(256, 6) void mscn_col_k(const TIN* __restrict__ src,
                                                     uint* __restrict__ xn_out,
                                                     __half* __restrict__ down_out,
                                                     WParams wp,
                                                     float* __restrict__ rgam,
                                                     float* __restrict__ gam) {
    constexpr int ROW_W = 132, H_OUT = 42, H_IN = H_OUT + 6, RPT = H_OUT / 2;
    constexpr int NTX = (S + 255) / 256, NTY = (S + H_OUT - 1) / H_OUT;
    constexpr int NBLK = 32 * NTX * NTY;

    if constexpr (TABLES) {
        if (blockIdx.x >= (unsigned)NBLK) {
            int i = (blockIdx.x - NBLK) * 256 + threadIdx.x;
            if (i < NTAB) {
                double g = 0.2 + (double)i * 0.001;
                double v = exp(2.0 * lgamma(2.0 / g) - lgamma(1.0 / g) - lgamma(3.0 / g));
                rgam[i] = (float)v;
                gam[i]  = (float)g;
            }
            return;
        }
    }

    __shared__ uint tin[ROW_W * H_IN];   // 25.3 KB

    const int tid = threadIdx.x;
    const int bid = blockIdx.x;
    const int b  = bid / (NTX * NTY);
    const int t2 = bid % (NTX * NTY);
    const int x0 = min((t2 / NTY) * 256, S - 256);
    const int y0 = min((t2 % NTY) * H_OUT, S - H_OUT);

    const float* w1 = wp.w1;
    uint wA[4], wB[4];
    wA[0] = pack2(0.f, w1[0]);   wA[1] = pack2(w1[1], w1[2]);
    wA[2] = pack2(w1[3], w1[4]); wA[3] = pack2(w1[5], w1[6]);
    wB[0] = pack2(w1[0], w1[1]); wB[1] = pack2(w1[2], w1[3]);
    wB[2] = pack2(w1[4], w1[5]); wB[3] = pack2(w1[6], 0.f);

    const TIN* img = src + (size_t)b * S * S;
    const bool interior = (x0 >= 4) && (x0 <= S - 260) && (y0 >= 3) && (y0 <= S - H_IN + 3);

    if (interior && sizeof(TIN) == 4) {
        // aligned float4 staging: 4 px -> 2 words per op
        const float4* base = reinterpret_cast<const float4*>((const float*)img + (size_t)(y0 - 3) * S + (x0 - 4));
        const int f4row = S / 4;
        for (int i = tid; i < 66 * H_IN; i += 256) {
            int r = i / 66, k = i - r * 66;
            float4 v = base[(size_t)r * f4row + k];
            tin[r * ROW_W + 2 * k]     = pack2(v.x, v.y);
            tin[r * ROW_W + 2 * k + 1] = pack2(v.z, v.w);
        }
    } else {
        for (int i = tid; i < ROW_W * H_IN; i += 256) {
            int r = i / ROW_W, w = i - r * ROW_W;
            int gy = y0 + r - 3; gy = gy < 0 ? 0 : (gy >= S ? S - 1 : gy);
            int c0 = x0 - 4 + 2 * w; c0 = c0 < 0 ? 0 : (c0 >= S ? S - 1 : c0);
            int c1 = x0 - 3 + 2 * w; c1 = c1 < 0 ? 0 : (c1 >= S ? S - 1 : c1);
            const TIN* rp = img + (size_t)gy * S;
            tin[i] = pack2((float)rp[c0], (float)rp[c1]);
        }
    }
    __syncthreads();

    const int g = tid >> 7, c = tid & 127;
    const int R0 = g * RPT;

    auto horiz = [&](int row, f2v& o1, f2v& o2) {
        const uint* pw = &tin[row * ROW_W + c];
        uint q0 = pw[0], q1 = pw[1], q2 = pw[2], q3 = pw[3], q4 = pw[4];
        uint p0 = pkmul(q0, q0), p1 = pkmul(q1, q1), p2 = pkmul(q2, q2),
             p3 = pkmul(q3, q3), p4 = pkmul(q4, q4);
        float s1A = fdot2f(q3, wA[3], fdot2f(q2, wA[2], fdot2f(q1, wA[1], fdot2f(q0, wA[0], 0.f))));
        float s2A = fdot2f(p3, wA[3], fdot2f(p2, wA[2], fdot2f(p1, wA[1], fdot2f(p0, wA[0], 0.f))));
        float s1B = fdot2f(q4, wB[3], fdot2f(q3, wB[2], fdot2f(q2, wB[1], fdot2f(q1, wB[0], 0.f))));
        float s2B = fdot2f(p4, wB[3], fdot2f(p3, wB[2], fdot2f(p2, wB[1], fdot2f(p1, wB[0], 0.f))));
        o1 = (f2v){s1A, s1B};
        o2 = (f2v){s2A, s2B};
    };

    f2v r1[7], r2[7];
#pragma unroll
    for (int ir = 0; ir < 6; ir++) horiz(R0 + ir, r1[ir], r2[ir]);

    uint* xnp = xn_out + ((((size_t)b * S + y0 + R0) * S + x0) >> 1) + c;
#pragma unroll
    for (int u = 0; u < RPT; u++) {
        horiz(R0 + u + 6, r1[(u + 6) % 7], r2[(u + 6) % 7]);
        f2v a1 = (f2v)(0.f), a2 = (f2v)(0.f);
#pragma unroll
        for (int dy = 0; dy < 7; dy++) {
            a1 += r1[(u + dy) % 7] * w1[dy];
            a2 += r2[(u + dy) % 7] * w1[dy];
        }
        uint qc = tin[(R0 + u + 3) * ROW_W + c + 2];
        float v0a = flo(qc), v0b = fhi(qc);
        float xa = (v0a - a1.x) * rcpf(sqrtf(fabsf(a2.x - a1.x * a1.x)) + 1.f);
        float xb = (v0b - a1.y) * rcpf(sqrtf(fabsf(a2.y - a1.y * a1.y)) + 1.f);
        xnp[(size_t)u * (S / 2)] = pack2(xa, xb);
    }

    if constexpr (FUSE_DOWN) {
        const float* wd = wp.wd;
        const int d = tid & 127, hf = tid >> 7;
        const int Xd = x0 / 2 + d;
        const float mL = (x0 + 2 * d - 1 >= 0) ? 1.f : 0.f;
#pragma unroll
        for (int jj = 0; jj <= RPT / 2; jj++) {
            int j = 2 * jj + hf;
            if (j >= RPT) continue;
            int Yd = y0 / 2 + j;
            float acc = 0.f;
#pragma unroll
            for (int a = 0; a < 3; a++) {
                int gy = 2 * Yd - 1 + a;
                if (gy < 0) continue;                  // zero pad (uniform)
                int tr = gy - y0 + 3;
                uint u1 = tin[tr * ROW_W + d + 1];
                uint u2 = tin[tr * ROW_W + d + 2];
                float rs = wd[0] * fhi(u1) * mL + wd[1] * flo(u2) + wd[2] * fhi(u2);
                acc += wd[a] * rs;
            }
            down_out[((size_t)b * (S / 2) + Yd) * (S / 2) + Xd] = __float2half(acc);
        }
    }
}

// ---------------------------------------------------------------------------
// AGGD features: packed pixel-pair sums, sign-bit counts, binary-search lookup.
// ---------------------------------------------------------------------------
template <int BS>
__global__ __launch_bounds__(256) void feat2_k(const __half* __restrict__ xnimg, int S,
                                               const float* __restrict__ rgam,
                                               const float* __restrict__ gam,
                                               float* __restrict__ dfeat, int foff) {
    constexpr int WROW = BS / 2;
    constexpr int NWORD = BS * BS / 2;
    constexpr int NITER = (NWORD + 255) / 256;
    __shared__ uint xs[NWORD];
    __shared__ float red[4 * 20];
    __shared__ float tot[20];

    const int tid = threadIdx.x;
    const int b   = blockIdx.x / 100;
    const int blk = blockIdx.x % 100;
    const int by  = (blk / 10) * BS;
    const int bx  = (blk % 10) * BS;

    const uint* gw = (const uint*)xnimg;
    for (int i = tid; i < NWORD; i += 256) {
        int y = i / WROW, w = i - y * WROW;
        xs[i] = gw[((((size_t)b * S + by + y) * S + bx) >> 1) + w];
    }
    __syncthreads();

    float ssq[5], sab[5], ssg[5];
    uint  cnt[5];
#pragma unroll
    for (int v = 0; v < 5; v++) { ssq[v] = sab[v] = ssg[v] = 0.f; cnt[v] = 0u; }

    const uint ONE2 = 0x3C003C00u;

    for (int k = 0; k < NITER; k++) {
        int idx = tid + k * 256;
        if (idx * 2 < BS * BS) {
            int p0 = idx * 2;
            int y = p0 / BS;
            int x = p0 - y * BS;
            int w0i = x >> 1;
            int wm = w0i ? w0i - 1 : WROW - 1;
            int wp = (w0i + 1 == WROW) ? 0 : w0i + 1;
            int ym1 = y ? y - 1 : BS - 1;
            int rb = y * WROW, rbm = ym1 * WROW;
            uint V0 = xs[rb + w0i];
            uint WL = xs[rb + wm];
            uint AL = xs[rbm + wm];
            uint AC = xs[rbm + w0i];
            uint AR = xs[rbm + wp];
            uint vv[5];
            vv[0] = V0;
            vv[1] = pkmul(V0, algn16(V0, WL));
            vv[2] = pkmul(V0, AC);
            vv[3] = pkmul(V0, algn16(AC, AL));
            vv[4] = pkmul(V0, algn16(AR, AC));
#pragma unroll
            for (int v = 0; v < 5; v++) {
                uint av = vv[v] & 0x7FFF7FFFu;
                ssq[v] = fdot2f(vv[v], vv[v], ssq[v]);
                sab[v] = fdot2f(av, ONE2, sab[v]);
                ssg[v] = fdot2f(vv[v], av, ssg[v]);
                cnt[v] += (vv[v] >> 15) & 0x00010001u;
            }
        }
    }

    const int wid = tid >> 6, lane = tid & 63;
#pragma unroll
    for (int v = 0; v < 5; v++) {
        float a = ssq[v], bb = sab[v], cc = ssg[v];
        float dd = (float)((cnt[v] & 0xFFFFu) + (cnt[v] >> 16));
        for (int off = 32; off >= 1; off >>= 1) {
            a += __shfl_down(a, off); bb += __shfl_down(bb, off);
            cc += __shfl_down(cc, off); dd += __shfl_down(dd, off);
        }
        if (lane == 0) {
            red[wid * 20 + v]      = a;
            red[wid * 20 + 5 + v]  = bb;
            red[wid * 20 + 10 + v] = cc;
            red[wid * 20 + 15 + v] = dd;
        }
    }
    __syncthreads();
    if (tid < 20) tot[tid] = red[tid] + red[20 + tid] + red[40 + tid] + red[60 + tid];
    __syncthreads();

    if (tid < 5) {
        const int v = tid;
        const float N = (float)(BS * BS);
        float ssqv = tot[v], sabv = tot[5 + v], ssgv = tot[10 + v], clv = tot[15 + v];
        float sql = fmaxf(0.5f * (ssqv - ssgv), 0.f);
        float sqr = fmaxf(0.5f * (ssqv + ssgv), 0.f);
        float cl = fmaxf(clv, 1.f), cr = fmaxf(N - clv, 1.f);
        float lstd = sqrtf(sql / cl), rstd = sqrtf(sqr / cr);
        float gh = lstd / fmaxf(rstd, 1e-12f);
        float mabs = sabv / N, msq = ssqv / N;
        float rhat = (mabs * mabs) / fmaxf(msq, 1e-12f);
        float gh2 = gh * gh;
        float target = rhat * (gh * gh2 + 1.f) * (gh + 1.f) / ((gh2 + 1.f) * (gh2 + 1.f));

        int lo = 0, hi = NTAB - 1, j = NTAB;
        while (lo <= hi) {
            int mid = (lo + hi) >> 1;
            if (rgam[mid] >= target) { j = mid; hi = mid - 1; } else lo = mid + 1;
        }
        int i0 = j > 0 ? j - 1 : 0;
        int i1 = j < NTAB ? j : NTAB - 1;
        float d0 = fabsf(rgam[i0] - target);
        float d1 = fabsf(rgam[i1] - target);
        int bi = (d1 < d0) ? i1 : i0;

        float alpha = gam[bi];
        float conv  = expf(0.5f * (lgammaf(1.f / alpha) - lgammaf(3.f / alpha)));
        float bl = lstd * conv, br = rstd * conv;
        float* outp = dfeat + ((size_t)b * 100 + blk) * 36 + foff;
        if (v == 0) {
            outp[0] = alpha;
            outp[1] = 0.5f * (bl + br);
        } else {
            float mean = (br - bl) * expf(lgammaf(2.f / alpha) - lgammaf(1.f / alpha));
            int base = 2 + (v - 1) * 4;
            outp[base + 0] = alpha; outp[base + 1] = mean;
            outp[base + 2] = bl;    outp[base + 3] = br;
        }
    }
}

// ---------------------------------------------------------------------------
// Per-batch stats + parallel SPD forward elimination.
// ---------------------------------------------------------------------------
__global__ __launch_bounds__(256) void final_k(const float* __restrict__ dfeat,
                                               const float* __restrict__ mu_pris,
                                               const float* __restrict__ cov_pris,
                                               float* __restrict__ out) {
    __shared__ float  ds[3600];
    __shared__ float  mu[36];
    __shared__ double M[36][37];
    __shared__ double rhs[36];
    __shared__ double qacc;
    const int b = blockIdx.x, tid = threadIdx.x;
    const float* src = dfeat + (size_t)b * 3600;
    for (int i = tid; i < 3600; i += 256) ds[i] = src[i];
    __syncthreads();
    if (tid < 36) {
        float s = 0.f;
        for (int n = 0; n < 100; n++) s += ds[n * 36 + tid];
        mu[tid] = s / 100.f;
    }
    __syncthreads();
    for (int i = tid; i < 3600; i += 256) ds[i] -= mu[i % 36];
    if (tid < 36) rhs[tid] = (double)mu_pris[tid] - (double)mu[tid];
    if (tid == 0) qacc = 0.0;
    __syncthreads();
    for (int e = tid; e < 1296; e += 256) {
        int f = e / 36, g = e % 36;
        float s = 0.f;
        for (int n = 0; n < 100; n++) s += ds[n * 36 + f] * ds[n * 36 + g];
        M[f][g] = 0.5 * ((double)cov_pris[e] + (double)(s / 99.f));
    }
    __syncthreads();
    for (int j = 0; j < 36; j++) {
        if (tid == 0) qacc += rhs[j] * rhs[j] / M[j][j];
        int i = j + 1 + tid;
        if (i < 36) {
            double L = M[i][j] / M[j][j];
            for (int k = j; k < 36; k++) M[i][k] -= L * M[j][k];
            rhs[i] -= L * rhs[j];
        }
        __syncthreads();
    }
    if (tid == 0) out[b] = sqrtf((float)(qacc > 0.0 ? qacc : 0.0));
}

// ---------------------------------------------------------------------------
static WParams make_weights() {
    WParams p;
    double wt[7], s = 0.0; const double sg = 7.0 / 6.0;
    for (int i = 0; i < 7; i++) { double d = i - 3; wt[i] = exp(-d * d / (2.0 * sg * sg)); s += wt[i]; }
    for (int i = 0; i < 7; i++) p.w1[i] = (float)(wt[i] / s);
    double e1 = exp(-2.0), sd = 1.0 + 2.0 * e1;
    p.wd[0] = p.wd[2] = (float)(e1 / sd);
    p.wd[1] = (float)(1.0 / sd);
    return p;
}

extern "C" void kernel_launch(void* const* d_in, const int* in_sizes, int n_in,
                              void* d_out, int out_size, void* d_ws, size_t ws_size,
                              hipStream_t stream) {
    const float* X        = (const float*)d_in[0];  // [32,1,960,960]
    const float* mu_pris  = (const float*)d_in[1];  // [36]
    const float* cov_pris = (const float*)d_in[2];  // [36,36]
    float* out = (float*)d_out;                     // [32]

    char* ws = (char*)d_ws;
    float*  rgam   = (float*)(ws);                      // 9801 f
    float*  gam    = (float*)(ws + 39424);
    float*  dfeat  = (float*)(ws + 78848);              // 32*100*36 f
    __half* xn960  = (__half*)(ws + 539648);            // 32*960*960 h
    __half* img480 = (__half*)(ws + 59522048);          // 32*480*480 h
    __half* xn480  = (__half*)(ws + 74267648);          // 32*480*480 h

    WParams wp = make_weights();

    // 960: NTX=4, NTY=23 -> 2944 blocks (+39 table-builder blocks)
    constexpr int NB960 = 32 * 4 * 23;
    constexpr int TBLB  = (NTAB + 255) / 256;
    mscn_col_k<960, true,  true,  float ><<<NB960 + TBLB, 256, 0, stream>>>(
        X, (uint*)xn960, img480, wp, rgam, gam);
    // 480: NTX=2, NTY=12 -> 768 blocks
    mscn_col_k<480, false, false, __half><<<32 * 2 * 12, 256, 0, stream>>>(
        img480, (uint*)xn480, nullptr, wp, rgam, gam);
    feat2_k<96><<<3200, 256, 0, stream>>>(xn960, 960, rgam, gam, dfeat, 0);
    feat2_k<48><<<3200, 256, 0, stream>>>(xn480, 480, rgam, gam, dfeat, 18);
    final_k<<<32, 256, 0, stream>>>(dfeat, mu_pris, cov_pris, out);
}

// Round 8
// 207.059 us; speedup vs baseline: 6.8368x; 1.0781x over previous
//
#include <hip/hip_runtime.h>
#include <hip/hip_fp16.h>
#include <math.h>

#define NTAB 9801
typedef unsigned int uint;
typedef float f2v __attribute__((ext_vector_type(2)));
typedef _Float16 h2v __attribute__((ext_vector_type(2)));

struct WParams { float w1[7]; float wd[3]; };

// ---------- packed-half helpers ----------
__device__ inline __half2 u2h2(uint u) { return __builtin_bit_cast(__half2, u); }
__device__ inline float flo(uint u) { return __low2float(u2h2(u)); }
__device__ inline float fhi(uint u) { return __high2float(u2h2(u)); }
__device__ inline uint pkmul(uint a, uint b) { return __builtin_bit_cast(uint, __hmul2(u2h2(a), u2h2(b))); }
__device__ inline uint pack2(float a, float b) {   // v_cvt_pkrtz_f16_f32
    return __builtin_bit_cast(uint, __builtin_amdgcn_cvt_pkrtz(a, b));
}
__device__ inline uint algn16(uint hi, uint lo) {   // (hi:lo)>>16 -> v_alignbit
    return (uint)((((unsigned long long)hi << 32) | lo) >> 16);
}
__device__ inline float fdot2f(uint a, uint b, float c) {
    return __builtin_amdgcn_fdot2(__builtin_bit_cast(h2v, a), __builtin_bit_cast(h2v, b), c, false);
}
__device__ inline float rcpf(float x) { return __builtin_amdgcn_rcpf(x); }

// ---------------------------------------------------------------------------
// MSCN body: f16-packed LDS tile (even-col origin x0-4), 2 out cols/thread,
// dot2 horizontal, packed-f32 vertical on a 7-deep ring. Optional fused
// 3x3/stride-2 downsample (f16, zero-pad). H_OUT=28 -> 17.9KB LDS, 8 blk/CU.
// ---------------------------------------------------------------------------
template <int S, bool FUSE_DOWN, typename TIN>
__device__ __forceinline__ void mscn_body(int bid, uint* tin,
                                          const TIN* __restrict__ src,
                                          uint* __restrict__ xn_out,
                                          __half* __restrict__ down_out,
                                          const WParams& wp) {
    constexpr int ROW_W = 132, H_OUT = 28, H_IN = H_OUT + 6, RPT = H_OUT / 2;
    constexpr int NTX = (S + 255) / 256, NTY = (S + H_OUT - 1) / H_OUT;

    const int tid = threadIdx.x;
    const int b  = bid / (NTX * NTY);
    const int t2 = bid % (NTX * NTY);
    const int x0 = min((t2 / NTY) * 256, S - 256);
    const int y0 = min((t2 % NTY) * H_OUT, S - H_OUT);

    const float* w1 = wp.w1;
    uint wA[4], wB[4];
    wA[0] = pack2(0.f, w1[0]);   wA[1] = pack2(w1[1], w1[2]);
    wA[2] = pack2(w1[3], w1[4]); wA[3] = pack2(w1[5], w1[6]);
    wB[0] = pack2(w1[0], w1[1]); wB[1] = pack2(w1[2], w1[3]);
    wB[2] = pack2(w1[4], w1[5]); wB[3] = pack2(w1[6], 0.f);

    const TIN* img = src + (size_t)b * S * S;
    const bool interior = (x0 >= 4) && (x0 <= S - 260) && (y0 >= 3) && (y0 <= S - H_IN + 3);

    if constexpr (sizeof(TIN) == 4) {
        if (interior) {
            const float4* base = reinterpret_cast<const float4*>(
                (const float*)img + (size_t)(y0 - 3) * S + (x0 - 4));
            const int f4row = S / 4;
            for (int i = tid; i < 66 * H_IN; i += 256) {
                int r = i / 66, k = i - r * 66;
                float4 v = base[(size_t)r * f4row + k];
                uint2 pr; pr.x = pack2(v.x, v.y); pr.y = pack2(v.z, v.w);
                *(uint2*)&tin[r * ROW_W + 2 * k] = pr;
            }
        } else {
            for (int i = tid; i < ROW_W * H_IN; i += 256) {
                int r = i / ROW_W, w = i - r * ROW_W;
                int gy = y0 + r - 3; gy = gy < 0 ? 0 : (gy >= S ? S - 1 : gy);
                int c0 = x0 - 4 + 2 * w; int c0c = c0 < 0 ? 0 : (c0 >= S ? S - 1 : c0);
                int c1 = c0 + 1;         int c1c = c1 < 0 ? 0 : (c1 >= S ? S - 1 : c1);
                const TIN* rp = img + (size_t)gy * S;
                tin[i] = pack2((float)rp[c0c], (float)rp[c1c]);
            }
        }
    } else {
        // f16 input: interior words are one aligned uint copy
        const uint* gw = (const uint*)img;
        for (int i = tid; i < ROW_W * H_IN; i += 256) {
            int r = i / ROW_W, w = i - r * ROW_W;
            int gy = y0 + r - 3; gy = gy < 0 ? 0 : (gy >= S ? S - 1 : gy);
            int c0 = x0 - 4 + 2 * w;
            if (c0 >= 0 && c0 + 1 < S) {
                tin[i] = gw[((size_t)gy * S + c0) >> 1];
            } else {
                int c0c = c0 < 0 ? 0 : (c0 >= S ? S - 1 : c0);
                int c1c = (c0 + 1) < 0 ? 0 : ((c0 + 1) >= S ? S - 1 : c0 + 1);
                const TIN* rp = img + (size_t)gy * S;
                tin[i] = pack2((float)rp[c0c], (float)rp[c1c]);
            }
        }
    }
    __syncthreads();

    const int g = tid >> 7, c = tid & 127;
    const int R0 = g * RPT;

    auto horiz = [&](int row, f2v& o1, f2v& o2) {
        const uint* pw = &tin[row * ROW_W + c];
        uint q0 = pw[0], q1 = pw[1], q2 = pw[2], q3 = pw[3], q4 = pw[4];
        uint p0 = pkmul(q0, q0), p1 = pkmul(q1, q1), p2 = pkmul(q2, q2),
             p3 = pkmul(q3, q3), p4 = pkmul(q4, q4);
        float s1A = fdot2f(q3, wA[3], fdot2f(q2, wA[2], fdot2f(q1, wA[1], fdot2f(q0, wA[0], 0.f))));
        float s2A = fdot2f(p3, wA[3], fdot2f(p2, wA[2], fdot2f(p1, wA[1], fdot2f(p0, wA[0], 0.f))));
        float s1B = fdot2f(q4, wB[3], fdot2f(q3, wB[2], fdot2f(q2, wB[1], fdot2f(q1, wB[0], 0.f))));
        float s2B = fdot2f(p4, wB[3], fdot2f(p3, wB[2], fdot2f(p2, wB[1], fdot2f(p1, wB[0], 0.f))));
        o1 = (f2v){s1A, s1B};
        o2 = (f2v){s2A, s2B};
    };

    f2v r1[7], r2[7];
#pragma unroll
    for (int ir = 0; ir < 6; ir++) horiz(R0 + ir, r1[ir], r2[ir]);

    uint* xnp = xn_out + ((((size_t)b * S + y0 + R0) * S + x0) >> 1) + c;
#pragma unroll
    for (int u = 0; u < RPT; u++) {
        horiz(R0 + u + 6, r1[(u + 6) % 7], r2[(u + 6) % 7]);
        f2v a1 = (f2v)(0.f), a2 = (f2v)(0.f);
#pragma unroll
        for (int dy = 0; dy < 7; dy++) {
            a1 += r1[(u + dy) % 7] * w1[dy];
            a2 += r2[(u + dy) % 7] * w1[dy];
        }
        uint qc = tin[(R0 + u + 3) * ROW_W + c + 2];
        float v0a = flo(qc), v0b = fhi(qc);
        float xa = (v0a - a1.x) * rcpf(sqrtf(fabsf(a2.x - a1.x * a1.x)) + 1.f);
        float xb = (v0b - a1.y) * rcpf(sqrtf(fabsf(a2.y - a1.y * a1.y)) + 1.f);
        xnp[(size_t)u * (S / 2)] = pack2(xa, xb);
    }

    if constexpr (FUSE_DOWN) {
        const float* wd = wp.wd;
        const int d = tid & 127, hf = tid >> 7;
        const int Xd = x0 / 2 + d;
        const float mL = (x0 + 2 * d - 1 >= 0) ? 1.f : 0.f;
#pragma unroll
        for (int jj = 0; jj < RPT / 2; jj++) {
            int j = 2 * jj + hf;
            int Yd = y0 / 2 + j;
            float acc = 0.f;
#pragma unroll
            for (int a = 0; a < 3; a++) {
                int gy = 2 * Yd - 1 + a;
                if (gy < 0) continue;                  // zero pad (uniform)
                int tr = gy - y0 + 3;
                uint u1 = tin[tr * ROW_W + d + 1];
                uint u2 = tin[tr * ROW_W + d + 2];
                float rs = wd[0] * fhi(u1) * mL + wd[1] * flo(u2) + wd[2] * fhi(u2);
                acc += wd[a] * rs;
            }
            down_out[((size_t)b * (S / 2) + Yd) * (S / 2) + Xd] = __float2half(acc);
        }
    }
}

// ---------------------------------------------------------------------------
// AGGD feature body: word-pair (4 px) inner loop, packed sums, sign-bit
// counts, binary-search table lookup by 5 tail threads.
// ---------------------------------------------------------------------------
template <int BS>
__device__ __forceinline__ void feat2_body(int bid, uint* xs, float* red, float* tot,
                                           const __half* __restrict__ xnimg, int S,
                                           const float* __restrict__ rgam,
                                           const float* __restrict__ gam,
                                           float* __restrict__ dfeat, int foff) {
    constexpr int WROW = BS / 2;          // words per row
    constexpr int NWORD = BS * BS / 2;
    constexpr int PAIRS = NWORD / 2;
    constexpr int PPR = WROW / 2;         // pairs per row

    const int tid = threadIdx.x;
    const int b   = bid / 100;
    const int blk = bid % 100;
    const int by  = (blk / 10) * BS;
    const int bx  = (blk % 10) * BS;

    // stage via uint4 (16B-aligned: S/2 and bx/2 are multiples of 4)
    const uint* gw = (const uint*)xnimg;
    uint4* xs4 = (uint4*)xs;
    constexpr int NW4 = NWORD / 4;
    constexpr int W4R = WROW / 4;
    for (int i = tid; i < NW4; i += 256) {
        int y = i / W4R, k = i - y * W4R;
        xs4[i] = *(const uint4*)&gw[((((size_t)b * S + by + y) * S + bx) >> 1) + 4 * k];
    }
    __syncthreads();

    float ssq[5], sab[5], ssg[5];
    uint  cnt[5];
#pragma unroll
    for (int v = 0; v < 5; v++) { ssq[v] = sab[v] = ssg[v] = 0.f; cnt[v] = 0u; }

    const uint ONE2 = 0x3C003C00u;

    for (int k = 0; k < (PAIRS + 255) / 256; k++) {
        int idx = tid + k * 256;
        if (idx < PAIRS) {                 // wave-uniform (PAIRS % 64 == 0)
            int y  = idx / PPR;
            int pr = idx - y * PPR;
            int w0 = pr * 2;
            int rb = y * WROW, rbm = (y ? y - 1 : BS - 1) * WROW;
            uint2 V = *(const uint2*)&xs[rb + w0];
            uint WL  = xs[rb  + (w0 ? w0 - 1 : WROW - 1)];
            uint2 A = *(const uint2*)&xs[rbm + w0];
            uint AL  = xs[rbm + (w0 ? w0 - 1 : WROW - 1)];
            uint AR  = xs[rbm + ((w0 + 2 == WROW) ? 0 : w0 + 2)];
            uint vA[5], vB[5];
            vA[0] = V.x;
            vA[1] = pkmul(V.x, algn16(V.x, WL));
            vA[2] = pkmul(V.x, A.x);
            vA[3] = pkmul(V.x, algn16(A.x, AL));
            vA[4] = pkmul(V.x, algn16(A.y, A.x));
            vB[0] = V.y;
            vB[1] = pkmul(V.y, algn16(V.y, V.x));
            vB[2] = pkmul(V.y, A.y);
            vB[3] = pkmul(V.y, algn16(A.y, A.x));
            vB[4] = pkmul(V.y, algn16(AR, A.y));
#pragma unroll
            for (int v = 0; v < 5; v++) {
                uint aA = vA[v] & 0x7FFF7FFFu, aB = vB[v] & 0x7FFF7FFFu;
                ssq[v] = fdot2f(vB[v], vB[v], fdot2f(vA[v], vA[v], ssq[v]));
                sab[v] = fdot2f(aB, ONE2, fdot2f(aA, ONE2, sab[v]));
                ssg[v] = fdot2f(vB[v], aB, fdot2f(vA[v], aA, ssg[v]));
                cnt[v] += ((vA[v] >> 15) & 0x00010001u) + ((vB[v] >> 15) & 0x00010001u);
            }
        }
    }

    const int wid = tid >> 6, lane = tid & 63;
#pragma unroll
    for (int v = 0; v < 5; v++) {
        float a = ssq[v], bb = sab[v], cc = ssg[v];
        float dd = (float)((cnt[v] & 0xFFFFu) + (cnt[v] >> 16));
        for (int off = 32; off >= 1; off >>= 1) {
            a += __shfl_down(a, off); bb += __shfl_down(bb, off);
            cc += __shfl_down(cc, off); dd += __shfl_down(dd, off);
        }
        if (lane == 0) {
            red[wid * 20 + v]      = a;
            red[wid * 20 + 5 + v]  = bb;
            red[wid * 20 + 10 + v] = cc;
            red[wid * 20 + 15 + v] = dd;
        }
    }
    __syncthreads();
    if (tid < 20) tot[tid] = red[tid] + red[20 + tid] + red[40 + tid] + red[60 + tid];
    __syncthreads();

    if (tid < 5) {
        const int v = tid;
        const float N = (float)(BS * BS);
        float ssqv = tot[v], sabv = tot[5 + v], ssgv = tot[10 + v], clv = tot[15 + v];
        float sql = fmaxf(0.5f * (ssqv - ssgv), 0.f);
        float sqr = fmaxf(0.5f * (ssqv + ssgv), 0.f);
        float cl = fmaxf(clv, 1.f), cr = fmaxf(N - clv, 1.f);
        float lstd = sqrtf(sql / cl), rstd = sqrtf(sqr / cr);
        float gh = lstd / fmaxf(rstd, 1e-12f);
        float mabs = sabv / N, msq = ssqv / N;
        float rhat = (mabs * mabs) / fmaxf(msq, 1e-12f);
        float gh2 = gh * gh;
        float target = rhat * (gh * gh2 + 1.f) * (gh + 1.f) / ((gh2 + 1.f) * (gh2 + 1.f));

        int lo = 0, hi = NTAB - 1, j = NTAB;
        while (lo <= hi) {
            int mid = (lo + hi) >> 1;
            if (rgam[mid] >= target) { j = mid; hi = mid - 1; } else lo = mid + 1;
        }
        int i0 = j > 0 ? j - 1 : 0;
        int i1 = j < NTAB ? j : NTAB - 1;
        float d0 = fabsf(rgam[i0] - target);
        float d1 = fabsf(rgam[i1] - target);
        int bi = (d1 < d0) ? i1 : i0;

        float alpha = gam[bi];
        float conv  = expf(0.5f * (lgammaf(1.f / alpha) - lgammaf(3.f / alpha)));
        float bl = lstd * conv, br = rstd * conv;
        float* outp = dfeat + ((size_t)b * 100 + blk) * 36 + foff;
        if (v == 0) {
            outp[0] = alpha;
            outp[1] = 0.5f * (bl + br);
        } else {
            float mean = (br - bl) * expf(lgammaf(2.f / alpha) - lgammaf(1.f / alpha));
            int base = 2 + (v - 1) * 4;
            outp[base + 0] = alpha; outp[base + 1] = mean;
            outp[base + 2] = bl;    outp[base + 3] = br;
        }
    }
}

// ---------------------------------------------------------------------------
// Kernel A: mscn960 (+fused downsample) + AGGD-table builder blocks.
// ---------------------------------------------------------------------------
__global__ __launch_bounds__(256, 8) void mscnA_k(const float* __restrict__ X,
                                                  uint* __restrict__ xn960,
                                                  __half* __restrict__ img480,
                                                  WParams wp,
                                                  float* __restrict__ rgam,
                                                  float* __restrict__ gam) {
    constexpr int NBLK = 32 * 4 * 35;   // NTX=4, NTY=35
    if (blockIdx.x >= (unsigned)NBLK) {
        int i = (blockIdx.x - NBLK) * 256 + threadIdx.x;
        if (i < NTAB) {
            double g = 0.2 + (double)i * 0.001;
            double v = exp(2.0 * lgamma(2.0 / g) - lgamma(1.0 / g) - lgamma(3.0 / g));
            rgam[i] = (float)v;
            gam[i]  = (float)g;
        }
        return;
    }
    __shared__ __align__(16) uint tin[132 * 34];
    mscn_body<960, true, float>(blockIdx.x, tin, X, xn960, img480, wp);
}

// ---------------------------------------------------------------------------
// Kernel B: fused mscn480 (blocks [0,1152)) + feat96 (blocks [1152, 4352)).
// Both depend only on kernel A's outputs -> run concurrently in one grid.
// ---------------------------------------------------------------------------
__global__ __launch_bounds__(256, 8) void launchB_k(const __half* __restrict__ img480,
                                                    uint* __restrict__ xn480,
                                                    const __half* __restrict__ xn960,
                                                    WParams wp,
                                                    const float* __restrict__ rgam,
                                                    const float* __restrict__ gam,
                                                    float* __restrict__ dfeat) {
    constexpr int NB480 = 32 * 2 * 18;   // NTX=2, NTY=18
    __shared__ __align__(16) uint smem[4608 + 100];
    if (blockIdx.x < (unsigned)NB480) {
        mscn_body<480, false, __half>(blockIdx.x, smem, img480, xn480, nullptr, wp);
    } else {
        float* red = (float*)(smem + 4608);
        float* tot = red + 80;
        feat2_body<96>(blockIdx.x - NB480, smem, red, tot, xn960, 960, rgam, gam, dfeat, 0);
    }
}

// ---------------------------------------------------------------------------
// Kernel C: feat48.
// ---------------------------------------------------------------------------
__global__ __launch_bounds__(256, 8) void feat48_k(const __half* __restrict__ xn480,
                                                   const float* __restrict__ rgam,
                                                   const float* __restrict__ gam,
                                                   float* __restrict__ dfeat) {
    __shared__ __align__(16) uint smem[1152 + 100];
    float* red = (float*)(smem + 1152);
    float* tot = red + 80;
    feat2_body<48>(blockIdx.x, smem, red, tot, xn480, 480, rgam, gam, dfeat, 18);
}

// ---------------------------------------------------------------------------
// Kernel D: per-batch stats + parallel SPD forward elimination.
// ---------------------------------------------------------------------------
__global__ __launch_bounds__(256) void final_k(const float* __restrict__ dfeat,
                                               const float* __restrict__ mu_pris,
                                               const float* __restrict__ cov_pris,
                                               float* __restrict__ out) {
    __shared__ float  ds[3600];
    __shared__ float  mu[36];
    __shared__ double M[36][37];
    __shared__ double rhs[36];
    __shared__ double qacc;
    const int b = blockIdx.x, tid = threadIdx.x;
    const float* src = dfeat + (size_t)b * 3600;
    for (int i = tid; i < 3600; i += 256) ds[i] = src[i];
    __syncthreads();
    if (tid < 36) {
        float s = 0.f;
        for (int n = 0; n < 100; n++) s += ds[n * 36 + tid];
        mu[tid] = s / 100.f;
    }
    __syncthreads();
    for (int i = tid; i < 3600; i += 256) ds[i] -= mu[i % 36];
    if (tid < 36) rhs[tid] = (double)mu_pris[tid] - (double)mu[tid];
    if (tid == 0) qacc = 0.0;
    __syncthreads();
    for (int e = tid; e < 1296; e += 256) {
        int f = e / 36, g = e % 36;
        float s = 0.f;
        for (int n = 0; n < 100; n++) s += ds[n * 36 + f] * ds[n * 36 + g];
        M[f][g] = 0.5 * ((double)cov_pris[e] + (double)(s / 99.f));
    }
    __syncthreads();
    for (int j = 0; j < 36; j++) {
        if (tid == 0) qacc += rhs[j] * rhs[j] / M[j][j];
        int i = j + 1 + tid;
        if (i < 36) {
            double L = M[i][j] / M[j][j];
            for (int k = j; k < 36; k++) M[i][k] -= L * M[j][k];
            rhs[i] -= L * rhs[j];
        }
        __syncthreads();
    }
    if (tid == 0) out[b] = sqrtf((float)(qacc > 0.0 ? qacc : 0.0));
}

// ---------------------------------------------------------------------------
static WParams make_weights() {
    WParams p;
    double wt[7], s = 0.0; const double sg = 7.0 / 6.0;
    for (int i = 0; i < 7; i++) { double d = i - 3; wt[i] = exp(-d * d / (2.0 * sg * sg)); s += wt[i]; }
    for (int i = 0; i < 7; i++) p.w1[i] = (float)(wt[i] / s);
    double e1 = exp(-2.0), sd = 1.0 + 2.0 * e1;
    p.wd[0] = p.wd[2] = (float)(e1 / sd);
    p.wd[1] = (float)(1.0 / sd);
    return p;
}

extern "C" void kernel_launch(void* const* d_in, const int* in_sizes, int n_in,
                              void* d_out, int out_size, void* d_ws, size_t ws_size,
                              hipStream_t stream) {
    const float* X        = (const float*)d_in[0];  // [32,1,960,960]
    const float* mu_pris  = (const float*)d_in[1];  // [36]
    const float* cov_pris = (const float*)d_in[2];  // [36,36]
    float* out = (float*)d_out;                     // [32]

    char* ws = (char*)d_ws;
    float*  rgam   = (float*)(ws);                      // 9801 f
    float*  gam    = (float*)(ws + 39424);
    float*  dfeat  = (float*)(ws + 78848);              // 32*100*36 f
    __half* xn960  = (__half*)(ws + 539648);            // 32*960*960 h
    __half* img480 = (__half*)(ws + 59522048);          // 32*480*480 h
    __half* xn480  = (__half*)(ws + 74267648);          // 32*480*480 h

    WParams wp = make_weights();

    constexpr int NB960 = 32 * 4 * 35;                  // 4480
    constexpr int TBLB  = (NTAB + 255) / 256;           // 39
    mscnA_k<<<NB960 + TBLB, 256, 0, stream>>>(X, (uint*)xn960, img480, wp, rgam, gam);
    launchB_k<<<32 * 2 * 18 + 3200, 256, 0, stream>>>(img480, (uint*)xn480, xn960, wp,
                                                      rgam, gam, dfeat);
    feat48_k<<<3200, 256, 0, stream>>>(xn480, rgam, gam, dfeat);
    final_k<<<32, 256, 0, stream>>>(dfeat, mu_pris, cov_pris, out);
}

// Round 9
// 199.126 us; speedup vs baseline: 7.1092x; 1.0398x over previous
//
#include <hip/hip_runtime.h>
#include <hip/hip_fp16.h>
#include <math.h>

#define NTAB 9801
typedef unsigned int uint;
typedef float f2v __attribute__((ext_vector_type(2)));
typedef _Float16 h2v __attribute__((ext_vector_type(2)));

struct WParams { float w1[7]; float wd[3]; };

// ---------- packed-half helpers ----------
__device__ inline __half2 u2h2(uint u) { return __builtin_bit_cast(__half2, u); }
__device__ inline float flo(uint u) { return __low2float(u2h2(u)); }
__device__ inline float fhi(uint u) { return __high2float(u2h2(u)); }
__device__ inline uint pkmul(uint a, uint b) { return __builtin_bit_cast(uint, __hmul2(u2h2(a), u2h2(b))); }
__device__ inline uint pack2(float a, float b) {   // v_cvt_pkrtz_f16_f32
    return __builtin_bit_cast(uint, __builtin_amdgcn_cvt_pkrtz(a, b));
}
__device__ inline uint algn16(uint hi, uint lo) {   // (hi:lo)>>16 -> v_alignbit
    return (uint)((((unsigned long long)hi << 32) | lo) >> 16);
}
__device__ inline float fdot2f(uint a, uint b, float c) {
    return __builtin_amdgcn_fdot2(__builtin_bit_cast(h2v, a), __builtin_bit_cast(h2v, b), c, false);
}
__device__ inline float rcpf(float x) { return __builtin_amdgcn_rcpf(x); }

// ---------------------------------------------------------------------------
// Kernel 0: AGGD gamma lookup tables (f64, matches numpy)
// ---------------------------------------------------------------------------
__global__ __launch_bounds__(256) void tables_k(float* __restrict__ rgam,
                                                float* __restrict__ gam) {
    int i = blockIdx.x * 256 + threadIdx.x;
    if (i >= NTAB) return;
    double g = 0.2 + (double)i * 0.001;
    double v = exp(2.0 * lgamma(2.0 / g) - lgamma(1.0 / g) - lgamma(3.0 / g));
    rgam[i] = (float)v;
    gam[i]  = (float)g;
}

// ---------------------------------------------------------------------------
// MSCN on an LDS tile: CW word-cols, tile width TW words, NG row-groups of
// RPG rows (last group has ORR-(NG-1)*RPG). Thread = (group, word-col).
// Writes xn (f16-packed) into xs[CW * ORR]. Caller guards tid < CW*NG.
// ---------------------------------------------------------------------------
template <int CW, int TW, int NG, int RPG, int ORR>
__device__ __forceinline__ void mscn_tile(const uint* tin, uint* xs,
                                          const float* w1, int tid) {
    constexpr int TAIL = ORR - (NG - 1) * RPG;
    const int g = tid / CW, c = tid - g * CW;
    const int R0 = g * RPG;

    uint wA[4], wB[4];
    wA[0] = pack2(0.f, w1[0]);   wA[1] = pack2(w1[1], w1[2]);
    wA[2] = pack2(w1[3], w1[4]); wA[3] = pack2(w1[5], w1[6]);
    wB[0] = pack2(w1[0], w1[1]); wB[1] = pack2(w1[2], w1[3]);
    wB[2] = pack2(w1[4], w1[5]); wB[3] = pack2(w1[6], 0.f);

    auto horiz = [&](int row, f2v& o1, f2v& o2) {
        const uint* pw = &tin[row * TW + c];
        uint q0 = pw[0], q1 = pw[1], q2 = pw[2], q3 = pw[3], q4 = pw[4];
        uint p0 = pkmul(q0, q0), p1 = pkmul(q1, q1), p2 = pkmul(q2, q2),
             p3 = pkmul(q3, q3), p4 = pkmul(q4, q4);
        float s1A = fdot2f(q3, wA[3], fdot2f(q2, wA[2], fdot2f(q1, wA[1], fdot2f(q0, wA[0], 0.f))));
        float s2A = fdot2f(p3, wA[3], fdot2f(p2, wA[2], fdot2f(p1, wA[1], fdot2f(p0, wA[0], 0.f))));
        float s1B = fdot2f(q4, wB[3], fdot2f(q3, wB[2], fdot2f(q2, wB[1], fdot2f(q1, wB[0], 0.f))));
        float s2B = fdot2f(p4, wB[3], fdot2f(p3, wB[2], fdot2f(p2, wB[1], fdot2f(p1, wB[0], 0.f))));
        o1 = (f2v){s1A, s1B};
        o2 = (f2v){s2A, s2B};
    };

    f2v r1[7], r2[7];
#pragma unroll
    for (int ir = 0; ir < 6; ir++) horiz(R0 + ir, r1[ir], r2[ir]);

#define MSCN_STEP(u)                                                          \
    {                                                                         \
        horiz(R0 + (u) + 6, r1[((u) + 6) % 7], r2[((u) + 6) % 7]);            \
        f2v a1 = (f2v)(0.f), a2 = (f2v)(0.f);                                 \
        _Pragma("unroll")                                                     \
        for (int dy = 0; dy < 7; dy++) {                                      \
            a1 += r1[((u) + dy) % 7] * w1[dy];                                \
            a2 += r2[((u) + dy) % 7] * w1[dy];                                \
        }                                                                     \
        uint qc = tin[(R0 + (u) + 3) * TW + c + 2];                           \
        float v0a = flo(qc), v0b = fhi(qc);                                   \
        float xa = (v0a - a1.x) * rcpf(sqrtf(fabsf(a2.x - a1.x * a1.x)) + 1.f);\
        float xb = (v0b - a1.y) * rcpf(sqrtf(fabsf(a2.y - a1.y * a1.y)) + 1.f);\
        xs[(R0 + (u)) * CW + c] = pack2(xa, xb);                              \
    }

#pragma unroll
    for (int u = 0; u < TAIL; u++) MSCN_STEP(u)
    if constexpr (TAIL < RPG) {
        if (g < NG - 1) {
#pragma unroll
            for (int u = TAIL; u < RPG; u++) MSCN_STEP(u)
        }
    }
#undef MSCN_STEP
}

// ---------------------------------------------------------------------------
// AGGD feature core on an LDS xn tile: word-pair inner loop, packed sums,
// sign-bit counts, binary-search table lookup by 5 tail threads.
// ---------------------------------------------------------------------------
template <int BS>
__device__ __forceinline__ void feat_core(const uint* xs, float* red, float* tot,
                                          int b, int blk,
                                          const float* __restrict__ rgam,
                                          const float* __restrict__ gam,
                                          float* __restrict__ dfeat, int foff) {
    constexpr int WROW = BS / 2;
    constexpr int PAIRS = BS * BS / 4;
    constexpr int PPR = WROW / 2;
    const int tid = threadIdx.x;

    float ssq[5], sab[5], ssg[5];
    uint  cnt[5];
#pragma unroll
    for (int v = 0; v < 5; v++) { ssq[v] = sab[v] = ssg[v] = 0.f; cnt[v] = 0u; }

    const uint ONE2 = 0x3C003C00u;

    for (int k = 0; k < (PAIRS + 255) / 256; k++) {
        int idx = tid + k * 256;
        if (idx < PAIRS) {                 // wave-uniform (PAIRS % 64 == 0)
            int y  = idx / PPR;
            int pr = idx - y * PPR;
            int w0 = pr * 2;
            int rb = y * WROW, rbm = (y ? y - 1 : BS - 1) * WROW;
            uint2 V = *(const uint2*)&xs[rb + w0];
            uint WL  = xs[rb  + (w0 ? w0 - 1 : WROW - 1)];
            uint2 A = *(const uint2*)&xs[rbm + w0];
            uint AL  = xs[rbm + (w0 ? w0 - 1 : WROW - 1)];
            uint AR  = xs[rbm + ((w0 + 2 == WROW) ? 0 : w0 + 2)];
            uint vA[5], vB[5];
            vA[0] = V.x;
            vA[1] = pkmul(V.x, algn16(V.x, WL));
            vA[2] = pkmul(V.x, A.x);
            vA[3] = pkmul(V.x, algn16(A.x, AL));
            vA[4] = pkmul(V.x, algn16(A.y, A.x));
            vB[0] = V.y;
            vB[1] = pkmul(V.y, algn16(V.y, V.x));
            vB[2] = pkmul(V.y, A.y);
            vB[3] = pkmul(V.y, algn16(A.y, A.x));
            vB[4] = pkmul(V.y, algn16(AR, A.y));
#pragma unroll
            for (int v = 0; v < 5; v++) {
                uint aA = vA[v] & 0x7FFF7FFFu, aB = vB[v] & 0x7FFF7FFFu;
                ssq[v] = fdot2f(vB[v], vB[v], fdot2f(vA[v], vA[v], ssq[v]));
                sab[v] = fdot2f(aB, ONE2, fdot2f(aA, ONE2, sab[v]));
                ssg[v] = fdot2f(vB[v], aB, fdot2f(vA[v], aA, ssg[v]));
                cnt[v] += ((vA[v] >> 15) & 0x00010001u) + ((vB[v] >> 15) & 0x00010001u);
            }
        }
    }

    const int wid = tid >> 6, lane = tid & 63;
#pragma unroll
    for (int v = 0; v < 5; v++) {
        float a = ssq[v], bb = sab[v], cc = ssg[v];
        float dd = (float)((cnt[v] & 0xFFFFu) + (cnt[v] >> 16));
        for (int off = 32; off >= 1; off >>= 1) {
            a += __shfl_down(a, off); bb += __shfl_down(bb, off);
            cc += __shfl_down(cc, off); dd += __shfl_down(dd, off);
        }
        if (lane == 0) {
            red[wid * 20 + v]      = a;
            red[wid * 20 + 5 + v]  = bb;
            red[wid * 20 + 10 + v] = cc;
            red[wid * 20 + 15 + v] = dd;
        }
    }
    __syncthreads();
    if (tid < 20) tot[tid] = red[tid] + red[20 + tid] + red[40 + tid] + red[60 + tid];
    __syncthreads();

    if (tid < 5) {
        const int v = tid;
        const float N = (float)(BS * BS);
        float ssqv = tot[v], sabv = tot[5 + v], ssgv = tot[10 + v], clv = tot[15 + v];
        float sql = fmaxf(0.5f * (ssqv - ssgv), 0.f);
        float sqr = fmaxf(0.5f * (ssqv + ssgv), 0.f);
        float cl = fmaxf(clv, 1.f), cr = fmaxf(N - clv, 1.f);
        float lstd = sqrtf(sql / cl), rstd = sqrtf(sqr / cr);
        float gh = lstd / fmaxf(rstd, 1e-12f);
        float mabs = sabv / N, msq = ssqv / N;
        float rhat = (mabs * mabs) / fmaxf(msq, 1e-12f);
        float gh2 = gh * gh;
        float target = rhat * (gh * gh2 + 1.f) * (gh + 1.f) / ((gh2 + 1.f) * (gh2 + 1.f));

        int lo = 0, hi = NTAB - 1, j = NTAB;
        while (lo <= hi) {
            int mid = (lo + hi) >> 1;
            if (rgam[mid] >= target) { j = mid; hi = mid - 1; } else lo = mid + 1;
        }
        int i0 = j > 0 ? j - 1 : 0;
        int i1 = j < NTAB ? j : NTAB - 1;
        float d0 = fabsf(rgam[i0] - target);
        float d1 = fabsf(rgam[i1] - target);
        int bi = (d1 < d0) ? i1 : i0;

        float alpha = gam[bi];
        float conv  = expf(0.5f * (lgammaf(1.f / alpha) - lgammaf(3.f / alpha)));
        float bl = lstd * conv, br = rstd * conv;
        float* outp = dfeat + ((size_t)b * 100 + blk) * 36 + foff;
        if (v == 0) {
            outp[0] = alpha;
            outp[1] = 0.5f * (bl + br);
        } else {
            float mean = (br - bl) * expf(lgammaf(2.f / alpha) - lgammaf(1.f / alpha));
            int base = 2 + (v - 1) * 4;
            outp[base + 0] = alpha; outp[base + 1] = mean;
            outp[base + 2] = bl;    outp[base + 3] = br;
        }
    }
}

// ---------------------------------------------------------------------------
// Kernel 1: fully fused scale-1: per 96x96 block, stage 102x102 input tile,
// MSCN -> LDS, fused 3x3/stride-2 downsample -> img480, AGGD -> dfeat[0:18].
// No xn global round-trip. LDS ~40KB -> 4 blocks/CU.
// ---------------------------------------------------------------------------
__global__ __launch_bounds__(256, 4) void fused960_k(const float* __restrict__ X,
                                                     __half* __restrict__ img480,
                                                     const float* __restrict__ rgam,
                                                     const float* __restrict__ gam,
                                                     float* __restrict__ dfeat,
                                                     WParams wp) {
    __shared__ __align__(16) uint tin[52 * 102];   // 21.2 KB: rows by-3..by+98, cols bx-4..bx+99
    __shared__ __align__(16) uint xs[48 * 96];     // 18.4 KB: xn tile
    __shared__ float red[80];
    __shared__ float tot[20];

    const int tid = threadIdx.x;
    const int b   = blockIdx.x / 100;
    const int blk = blockIdx.x % 100;
    const int br  = blk / 10, bc = blk % 10;
    const int by  = br * 96, bx = bc * 96;

    const float* img = X + (size_t)b * 960 * 960;
    const bool interior = (br >= 1) && (br <= 8) && (bc >= 1) && (bc <= 8);

    if (interior) {
        const float4* base = reinterpret_cast<const float4*>(
            img + (size_t)(by - 3) * 960 + (bx - 4));
        for (int i = tid; i < 26 * 102; i += 256) {
            int r = i / 26, k = i - r * 26;
            float4 v = base[(size_t)r * 240 + k];
            tin[r * 52 + 2 * k]     = pack2(v.x, v.y);
            tin[r * 52 + 2 * k + 1] = pack2(v.z, v.w);
        }
    } else {
        for (int i = tid; i < 52 * 102; i += 256) {
            int r = i / 52, w = i - r * 52;
            int gy = by + r - 3; gy = gy < 0 ? 0 : (gy > 959 ? 959 : gy);
            int c0 = bx - 4 + 2 * w; int c0c = c0 < 0 ? 0 : (c0 > 959 ? 959 : c0);
            int c1 = c0 + 1;         int c1c = c1 < 0 ? 0 : (c1 > 959 ? 959 : c1);
            const float* rp = img + (size_t)gy * 960;
            tin[i] = pack2(rp[c0c], rp[c1c]);
        }
    }
    __syncthreads();

    // MSCN: 48 word-cols x 5 row-groups (4x20 + 1x16) = 240 threads
    if (tid < 240) mscn_tile<48, 52, 5, 20, 96>(tin, xs, wp.w1, tid);

    // fused downsample (reads tin only): 48x48 outputs, 9 per thread
    {
        const float* wd = wp.wd;
#pragma unroll
        for (int k = 0; k < 9; k++) {
            int o = tid + k * 256;
            int j = o / 48, d = o - j * 48;
            int Yd = by / 2 + j, Xd = bx / 2 + d;
            float mL = (bx + 2 * d - 1 >= 0) ? 1.f : 0.f;
            float acc = 0.f;
#pragma unroll
            for (int a = 0; a < 3; a++) {
                int gy = 2 * Yd - 1 + a;
                if (gy < 0) continue;                 // zero pad
                int tr = gy - by + 3;
                uint u1 = tin[tr * 52 + d + 1];
                uint u2 = tin[tr * 52 + d + 2];
                acc += wd[a] * (wd[0] * fhi(u1) * mL + wd[1] * flo(u2) + wd[2] * fhi(u2));
            }
            img480[((size_t)b * 480 + Yd) * 480 + Xd] = __float2half(acc);
        }
    }
    __syncthreads();

    feat_core<96>(xs, red, tot, b, blk, rgam, gam, dfeat, 0);
}

// ---------------------------------------------------------------------------
// Kernel 2: fully fused scale-2: per 48x48 block, stage 54x54 f16 tile,
// MSCN -> LDS, AGGD -> dfeat[18:36].
// ---------------------------------------------------------------------------
__global__ __launch_bounds__(256, 8) void fused480_k(const __half* __restrict__ img480,
                                                     const float* __restrict__ rgam,
                                                     const float* __restrict__ gam,
                                                     float* __restrict__ dfeat,
                                                     WParams wp) {
    __shared__ __align__(16) uint tin[28 * 54];   // 6.0 KB: rows by-3..by+50, cols bx-4..bx+51
    __shared__ __align__(16) uint xs[24 * 48];    // 4.6 KB
    __shared__ float red[80];
    __shared__ float tot[20];

    const int tid = threadIdx.x;
    const int b   = blockIdx.x / 100;
    const int blk = blockIdx.x % 100;
    const int br  = blk / 10, bc = blk % 10;
    const int by  = br * 48, bx = bc * 48;

    const __half* img = img480 + (size_t)b * 480 * 480;
    const uint* gw = (const uint*)img;
    const bool interior = (br >= 1) && (br <= 8) && (bc >= 1) && (bc <= 8);

    if (interior) {
        for (int i = tid; i < 28 * 54; i += 256) {
            int r = i / 28, w = i - r * 28;
            tin[i] = gw[(((size_t)(by + r - 3) * 480 + (bx - 4)) >> 1) + w];
        }
    } else {
        for (int i = tid; i < 28 * 54; i += 256) {
            int r = i / 28, w = i - r * 28;
            int gy = by + r - 3; gy = gy < 0 ? 0 : (gy > 479 ? 479 : gy);
            int c0 = bx - 4 + 2 * w; int c0c = c0 < 0 ? 0 : (c0 > 479 ? 479 : c0);
            int c1 = c0 + 1;         int c1c = c1 < 0 ? 0 : (c1 > 479 ? 479 : c1);
            const __half* rp = img + (size_t)gy * 480;
            tin[i] = pack2(__half2float(rp[c0c]), __half2float(rp[c1c]));
        }
    }
    __syncthreads();

    // MSCN: 24 word-cols x 8 row-groups of 6 rows = 192 threads
    if (tid < 192) mscn_tile<24, 28, 8, 6, 48>(tin, xs, wp.w1, tid);
    __syncthreads();

    feat_core<48>(xs, red, tot, b, blk, rgam, gam, dfeat, 18);
}

// ---------------------------------------------------------------------------
// Kernel 3: per-batch stats + parallel SPD forward elimination.
// q = sum_j y_j^2 / d_j (forward elimination only, SPD -> no pivoting).
// ---------------------------------------------------------------------------
__global__ __launch_bounds__(256) void final_k(const float* __restrict__ dfeat,
                                               const float* __restrict__ mu_pris,
                                               const float* __restrict__ cov_pris,
                                               float* __restrict__ out) {
    __shared__ float  ds[3600];
    __shared__ float  mu[36];
    __shared__ double M[36][37];
    __shared__ double rhs[36];
    __shared__ double qacc;
    const int b = blockIdx.x, tid = threadIdx.x;
    const float* src = dfeat + (size_t)b * 3600;
    for (int i = tid; i < 3600; i += 256) ds[i] = src[i];
    __syncthreads();
    if (tid < 36) {
        float s = 0.f;
        for (int n = 0; n < 100; n++) s += ds[n * 36 + tid];
        mu[tid] = s / 100.f;
    }
    __syncthreads();
    for (int i = tid; i < 3600; i += 256) ds[i] -= mu[i % 36];
    if (tid < 36) rhs[tid] = (double)mu_pris[tid] - (double)mu[tid];
    if (tid == 0) qacc = 0.0;
    __syncthreads();
    for (int e = tid; e < 1296; e += 256) {
        int f = e / 36, g = e % 36;
        float s = 0.f;
        for (int n = 0; n < 100; n++) s += ds[n * 36 + f] * ds[n * 36 + g];
        M[f][g] = 0.5 * ((double)cov_pris[e] + (double)(s / 99.f));
    }
    __syncthreads();
    for (int j = 0; j < 36; j++) {
        if (tid == 0) qacc += rhs[j] * rhs[j] / M[j][j];
        int i = j + 1 + tid;
        if (i < 36) {
            double L = M[i][j] / M[j][j];
            for (int k = j; k < 36; k++) M[i][k] -= L * M[j][k];
            rhs[i] -= L * rhs[j];
        }
        __syncthreads();
    }
    if (tid == 0) out[b] = sqrtf((float)(qacc > 0.0 ? qacc : 0.0));
}

// ---------------------------------------------------------------------------
static WParams make_weights() {
    WParams p;
    double wt[7], s = 0.0; const double sg = 7.0 / 6.0;
    for (int i = 0; i < 7; i++) { double d = i - 3; wt[i] = exp(-d * d / (2.0 * sg * sg)); s += wt[i]; }
    for (int i = 0; i < 7; i++) p.w1[i] = (float)(wt[i] / s);
    double e1 = exp(-2.0), sd = 1.0 + 2.0 * e1;
    p.wd[0] = p.wd[2] = (float)(e1 / sd);
    p.wd[1] = (float)(1.0 / sd);
    return p;
}

extern "C" void kernel_launch(void* const* d_in, const int* in_sizes, int n_in,
                              void* d_out, int out_size, void* d_ws, size_t ws_size,
                              hipStream_t stream) {
    const float* X        = (const float*)d_in[0];  // [32,1,960,960]
    const float* mu_pris  = (const float*)d_in[1];  // [36]
    const float* cov_pris = (const float*)d_in[2];  // [36,36]
    float* out = (float*)d_out;                     // [32]

    char* ws = (char*)d_ws;
    float*  rgam   = (float*)(ws);                      // 9801 f
    float*  gam    = (float*)(ws + 39424);
    float*  dfeat  = (float*)(ws + 78848);              // 32*100*36 f
    __half* img480 = (__half*)(ws + 539648);            // 32*480*480 h

    WParams wp = make_weights();

    tables_k<<<(NTAB + 255) / 256, 256, 0, stream>>>(rgam, gam);
    fused960_k<<<3200, 256, 0, stream>>>(X, img480, rgam, gam, dfeat, wp);
    fused480_k<<<3200, 256, 0, stream>>>(img480, rgam, gam, dfeat, wp);
    final_k<<<32, 256, 0, stream>>>(dfeat, mu_pris, cov_pris, out);
}